// Round 1
// baseline (1617.807 us; speedup 1.0000x reference)
//
#include <hip/hip_runtime.h>
#include <math.h>

#define BB 4
#define NN 1024
#define DIMM 256
#define HEADS 8
#define DH 64
#define INNERD 512

__device__ __forceinline__ float gelu_f(float x) {
    return 0.5f * x * (1.0f + erff(x * 0.70710678118654752f));
}
__device__ __forceinline__ float leaky_f(float x) {
    return fmaxf(x, 0.01f * x);
}

// ---------------- K1: LayerNorm ----------------
__global__ __launch_bounds__(256) void ln_kernel(const float* __restrict__ feat,
                                                 const float* __restrict__ gamma,
                                                 const float* __restrict__ beta,
                                                 float* __restrict__ x) {
    int row = blockIdx.x;           // 0..4095
    int t = threadIdx.x;            // 0..255
    float v = feat[row * DIMM + t];
    float s = v, ss = v * v;
    #pragma unroll
    for (int off = 1; off < 64; off <<= 1) {
        s += __shfl_xor(s, off);
        ss += __shfl_xor(ss, off);
    }
    __shared__ float red[2][4];
    int w = t >> 6, lane = t & 63;
    if (lane == 0) { red[0][w] = s; red[1][w] = ss; }
    __syncthreads();
    s = red[0][0] + red[0][1] + red[0][2] + red[0][3];
    ss = red[1][0] + red[1][1] + red[1][2] + red[1][3];
    float mu = s * (1.0f / DIMM);
    float var = ss * (1.0f / DIMM) - mu * mu;
    float rs = rsqrtf(var + 1e-5f);
    x[row * DIMM + t] = (v - mu) * rs * gamma[t] + beta[t];
}

// ---------------- K2: QKV projection ----------------
// grid (256 row-tiles of 16, 6 col-chunks of 256), block 256
__global__ __launch_bounds__(256) void qkv_kernel(const float* __restrict__ x,
                                                  const float* __restrict__ Wqkv,
                                                  float* __restrict__ q,
                                                  float* __restrict__ k,
                                                  float* __restrict__ v) {
    __shared__ float xs[16][DIMM];
    int rt = blockIdx.x;
    int cbase = blockIdx.y * 256;
    int tid = threadIdx.x;
    for (int idx = tid; idx < 16 * DIMM; idx += 256) {
        int r = idx >> 8, c = idx & 255;
        xs[r][c] = x[(rt * 16 + r) * DIMM + c];
    }
    __syncthreads();
    int col = cbase + tid;
    float acc[16];
    #pragma unroll
    for (int r = 0; r < 16; ++r) acc[r] = 0.f;
    for (int kk = 0; kk < DIMM; kk += 4) {
        float w0 = Wqkv[(kk + 0) * 1536 + col];
        float w1 = Wqkv[(kk + 1) * 1536 + col];
        float w2 = Wqkv[(kk + 2) * 1536 + col];
        float w3 = Wqkv[(kk + 3) * 1536 + col];
        #pragma unroll
        for (int r = 0; r < 16; ++r) {
            float4 xv = *(const float4*)&xs[r][kk];
            acc[r] += xv.x * w0 + xv.y * w1 + xv.z * w2 + xv.w * w3;
        }
    }
    int part = col / INNERD;     // 0=q,1=k,2=v
    int cc = col % INNERD;
    int h = cc / DH, d = cc % DH;
    float* dst = part == 0 ? q : (part == 1 ? k : v);
    float sc = part == 0 ? 0.125f : 1.0f;   // fold dim_head^-0.5 into q
    #pragma unroll
    for (int r = 0; r < 16; ++r) {
        int g = rt * 16 + r;
        int bb = g >> 10, nn = g & 1023;
        dst[(((bb * HEADS + h) * NN) + nn) * DH + d] = acc[r] * sc;
    }
}

// ---------------- K3: pairwise delta MLP -> md (b,i,j,3) ----------------
__global__ __launch_bounds__(256) void dmlp_kernel(const float* __restrict__ xyz,
                                                   const float* __restrict__ Wp1,
                                                   const float* __restrict__ Wp2,
                                                   const float* __restrict__ Wn1,
                                                   const float* __restrict__ Wn2,
                                                   const float* __restrict__ Wc,
                                                   const float* __restrict__ bc,
                                                   float* __restrict__ md) {
    __shared__ float w_p1[48], w_p2[48], w_n1[48], w_n2[48], w_c[9], b_c[3];
    int tid = threadIdx.x;
    if (tid < 48) { w_p1[tid] = Wp1[tid]; w_n1[tid] = Wn1[tid];
                    w_p2[tid] = Wp2[tid]; w_n2[tid] = Wn2[tid]; }
    if (tid < 9) w_c[tid] = Wc[tid];
    if (tid < 3) b_c[tid] = bc[tid];
    __syncthreads();
    long e = (long)blockIdx.x * 256 + tid;   // b*N*N + i*N + j
    int j = (int)(e & (NN - 1));
    long t2 = e >> 10;
    int i = (int)(t2 & (NN - 1));
    int b = (int)(t2 >> 10);
    float d0 = xyz[(b * NN + j) * 3 + 0] - xyz[(b * NN + i) * 3 + 0];
    float d1 = xyz[(b * NN + j) * 3 + 1] - xyz[(b * NN + i) * 3 + 1];
    float d2 = xyz[(b * NN + j) * 3 + 2] - xyz[(b * NN + i) * 3 + 2];

    float p0, p1, p2, n0, n1, n2;
    {
        float r0 = fmaxf(d0, 0.f), r1 = fmaxf(d1, 0.f), r2 = fmaxf(d2, 0.f);
        float a0 = 0.f, a1 = 0.f, a2 = 0.f;
        #pragma unroll
        for (int m = 0; m < 16; ++m) {
            float t = r0 * w_p1[m] + r1 * w_p1[16 + m] + r2 * w_p1[32 + m];
            t = gelu_f(t);
            a0 += t * w_p2[m * 3 + 0];
            a1 += t * w_p2[m * 3 + 1];
            a2 += t * w_p2[m * 3 + 2];
        }
        p0 = leaky_f(a0); p1 = leaky_f(a1); p2 = leaky_f(a2);
    }
    {
        float r0 = fmaxf(-d0, 0.f), r1 = fmaxf(-d1, 0.f), r2 = fmaxf(-d2, 0.f);
        float a0 = 0.f, a1 = 0.f, a2 = 0.f;
        #pragma unroll
        for (int m = 0; m < 16; ++m) {
            float t = r0 * w_n1[m] + r1 * w_n1[16 + m] + r2 * w_n1[32 + m];
            t = gelu_f(t);
            a0 += t * w_n2[m * 3 + 0];
            a1 += t * w_n2[m * 3 + 1];
            a2 += t * w_n2[m * 3 + 2];
        }
        n0 = leaky_f(a0); n1 = leaky_f(a1); n2 = leaky_f(a2);
    }
    float pn0 = p0 * n0, pn1 = p1 * n1, pn2 = p2 * n2;
    float c0 = leaky_f(pn0 * w_c[0] + pn1 * w_c[3] + pn2 * w_c[6] + b_c[0]);
    float c1 = leaky_f(pn0 * w_c[1] + pn1 * w_c[4] + pn2 * w_c[7] + b_c[1]);
    float c2 = leaky_f(pn0 * w_c[2] + pn1 * w_c[5] + pn2 * w_c[8] + b_c[2]);
    long o = e * 3;
    md[o + 0] = c0 * d0;
    md[o + 1] = c1 * d1;
    md[o + 2] = c2 * d2;
}

// ---------------- K4: fused attention (scores, softmax, PV, wdelta, disp) ----------------
// grid (64 i-tiles, 8 heads, 4 batches), block 256 = 4 waves, 4 i-rows per wave
__global__ __launch_bounds__(256) void attn_kernel(const float* __restrict__ q,
                                                   const float* __restrict__ kk,
                                                   const float* __restrict__ vv,
                                                   const float* __restrict__ md,
                                                   const float* __restrict__ Wsp,
                                                   float* __restrict__ y) {
    int it = blockIdx.x, h = blockIdx.y, b = blockIdx.z;
    int tid = threadIdx.x;
    int w = tid >> 6, lane = tid & 63;
    __shared__ float qs[16][DH];
    __shared__ float KV[64 * 66];
    __shared__ float ps[4][4][64];
    const float* qp = q + (((long)b * HEADS + h) * NN) * DH;
    const float* kp = kk + (((long)b * HEADS + h) * NN) * DH;
    const float* vp = vv + (((long)b * HEADS + h) * NN) * DH;
    for (int idx = tid; idx < 16 * DH; idx += 256) {
        int r = idx >> 6, d = idx & 63;
        qs[r][d] = qp[(it * 16 + r) * DH + d];
    }

    float s[4][16];
    // ---- pass 1: scores (K staged transposed [d][j] to avoid bank conflicts) ----
    #pragma unroll
    for (int jt = 0; jt < 16; ++jt) {
        __syncthreads();
        #pragma unroll
        for (int idx = 0; idx < 16; ++idx) {
            int t2 = idx * 256 + tid;
            int j = t2 >> 6, d = t2 & 63;
            KV[d * 66 + j] = kp[(jt * 64 + j) * DH + d];
        }
        __syncthreads();
        float a0 = 0.f, a1 = 0.f, a2 = 0.f, a3 = 0.f;
        #pragma unroll
        for (int dd = 0; dd < 64; ++dd) {
            float kvv = KV[dd * 66 + lane];
            a0 += qs[w * 4 + 0][dd] * kvv;
            a1 += qs[w * 4 + 1][dd] * kvv;
            a2 += qs[w * 4 + 2][dd] * kvv;
            a3 += qs[w * 4 + 3][dd] * kvv;
        }
        s[0][jt] = a0; s[1][jt] = a1; s[2][jt] = a2; s[3][jt] = a3;
    }

    // ---- softmax stats per row ----
    float m[4], linv[4];
    #pragma unroll
    for (int r = 0; r < 4; ++r) {
        float mm = s[r][0];
        #pragma unroll
        for (int jt = 1; jt < 16; ++jt) mm = fmaxf(mm, s[r][jt]);
        #pragma unroll
        for (int off = 1; off < 64; off <<= 1) mm = fmaxf(mm, __shfl_xor(mm, off));
        float ll = 0.f;
        #pragma unroll
        for (int jt = 0; jt < 16; ++jt) ll += __expf(s[r][jt] - mm);
        #pragma unroll
        for (int off = 1; off < 64; off <<= 1) ll += __shfl_xor(ll, off);
        m[r] = mm; linv[r] = 1.0f / ll;
    }

    // ---- pass 2: PV + wdelta ----
    float o0 = 0.f, o1 = 0.f, o2 = 0.f, o3 = 0.f;
    float wd[4][3] = {};
    #pragma unroll
    for (int jt = 0; jt < 16; ++jt) {
        __syncthreads();
        #pragma unroll
        for (int idx = 0; idx < 16; ++idx) {
            int t2 = idx * 256 + tid;
            int j = t2 >> 6, d = t2 & 63;
            KV[j * 66 + d] = vp[(jt * 64 + j) * DH + d];
        }
        __syncthreads();
        #pragma unroll
        for (int r = 0; r < 4; ++r) {
            float p = __expf(s[r][jt] - m[r]) * linv[r];
            int ig = it * 16 + w * 4 + r;
            const float* mdp = md + (((long)b * NN + ig) * NN + jt * 64 + lane) * 3;
            wd[r][0] += p * mdp[0];
            wd[r][1] += p * mdp[1];
            wd[r][2] += p * mdp[2];
            ps[w][r][lane] = p;
        }
        // p written and read by the same wave: lockstep, no block barrier needed
        #pragma unroll
        for (int j2 = 0; j2 < 64; ++j2) {
            float vr = KV[j2 * 66 + lane];
            o0 += ps[w][0][j2] * vr;
            o1 += ps[w][1][j2] * vr;
            o2 += ps[w][2][j2] * vr;
            o3 += ps[w][3][j2] * vr;
        }
    }

    // ---- epilogue: reduce wdelta across lanes, disp = wd @ W_spatial, write y ----
    float oarr[4] = {o0, o1, o2, o3};
    #pragma unroll
    for (int r = 0; r < 4; ++r) {
        #pragma unroll
        for (int c = 0; c < 3; ++c) {
            float t = wd[r][c];
            #pragma unroll
            for (int off = 1; off < 64; off <<= 1) t += __shfl_xor(t, off);
            wd[r][c] = t;
        }
        float disp = wd[r][0] * Wsp[lane] + wd[r][1] * Wsp[64 + lane] + wd[r][2] * Wsp[128 + lane];
        int ig = it * 16 + w * 4 + r;
        y[(((long)b * NN + ig) * INNERD) + h * DH + lane] = oarr[r] + disp;
    }
}

// ---------------- K5: output projection + GELU + residual ----------------
// grid 512 blocks of 8 rows, block 256 (one col each)
__global__ __launch_bounds__(256) void out_kernel(const float* __restrict__ y,
                                                  const float* __restrict__ Wout,
                                                  const float* __restrict__ bout,
                                                  const float* __restrict__ feat,
                                                  float* __restrict__ out) {
    __shared__ float ys[8][INNERD];
    int rt = blockIdx.x;
    int tid = threadIdx.x;
    for (int idx = tid; idx < 8 * INNERD; idx += 256) {
        int r = idx >> 9, c = idx & 511;
        ys[r][c] = y[((long)rt * 8 + r) * INNERD + c];
    }
    __syncthreads();
    float acc[8] = {};
    for (int kk = 0; kk < INNERD; kk += 4) {
        float w0 = Wout[(kk + 0) * DIMM + tid];
        float w1 = Wout[(kk + 1) * DIMM + tid];
        float w2 = Wout[(kk + 2) * DIMM + tid];
        float w3 = Wout[(kk + 3) * DIMM + tid];
        #pragma unroll
        for (int r = 0; r < 8; ++r) {
            float4 yv = *(const float4*)&ys[r][kk];
            acc[r] += yv.x * w0 + yv.y * w1 + yv.z * w2 + yv.w * w3;
        }
    }
    float bo = bout[tid];
    #pragma unroll
    for (int r = 0; r < 8; ++r) {
        long g = (long)rt * 8 + r;
        float val = gelu_f(acc[r] + bo);
        out[g * DIMM + tid] = val + feat[g * DIMM + tid];
    }
}

extern "C" void kernel_launch(void* const* d_in, const int* in_sizes, int n_in,
                              void* d_out, int out_size, void* d_ws, size_t ws_size,
                              hipStream_t stream) {
    const float* xyzs  = (const float*)d_in[0];
    const float* feat  = (const float*)d_in[1];
    const float* gamma = (const float*)d_in[2];
    const float* beta  = (const float*)d_in[3];
    const float* Wqkv  = (const float*)d_in[4];
    const float* Wp1   = (const float*)d_in[5];
    const float* Wp2   = (const float*)d_in[6];
    const float* Wn1   = (const float*)d_in[7];
    const float* Wn2   = (const float*)d_in[8];
    const float* Wc    = (const float*)d_in[9];
    const float* bc    = (const float*)d_in[10];
    const float* Wsp   = (const float*)d_in[11];
    const float* Wout  = (const float*)d_in[12];
    const float* bout  = (const float*)d_in[13];
    float* out = (float*)d_out;
    float* ws = (float*)d_ws;

    // workspace layout (floats): x 1M | q 2M | k 2M | v 2M | y 2M | md 12M  = 84 MB
    float* x = ws;
    float* q = x + 1048576;
    float* k = q + 2097152;
    float* v = k + 2097152;
    float* y = v + 2097152;
    float* md = y + 2097152;

    ln_kernel<<<4096, 256, 0, stream>>>(feat, gamma, beta, x);
    qkv_kernel<<<dim3(256, 6), 256, 0, stream>>>(x, Wqkv, q, k, v);
    dmlp_kernel<<<16384, 256, 0, stream>>>(xyzs, Wp1, Wp2, Wn1, Wn2, Wc, bc, md);
    attn_kernel<<<dim3(64, HEADS, BB), 256, 0, stream>>>(q, k, v, md, Wsp, y);
    out_kernel<<<512, 256, 0, stream>>>(y, Wout, bout, feat, out);
}

// Round 2
// 368.427 us; speedup vs baseline: 4.3911x; 4.3911x over previous
//
#include <hip/hip_runtime.h>
#include <hip/hip_bf16.h>
#include <math.h>

#define BB 4
#define NN 1024
#define DIMM 256
#define HEADS 8
#define DH 64
#define INNERD 512
#define NT 16

typedef __bf16 bf16x8 __attribute__((ext_vector_type(8)));
typedef float f32x4 __attribute__((ext_vector_type(4)));

__device__ __forceinline__ float gelu_f(float x) {
    return 0.5f * x * (1.0f + erff(x * 0.70710678118654752f));
}
__device__ __forceinline__ float leaky_f(float x) {
    return fmaxf(x, 0.01f * x);
}

// ---------------- K1: LayerNorm ----------------
__global__ __launch_bounds__(256) void ln_kernel(const float* __restrict__ feat,
                                                 const float* __restrict__ gamma,
                                                 const float* __restrict__ beta,
                                                 float* __restrict__ x) {
    int row = blockIdx.x;
    int t = threadIdx.x;
    float v = feat[row * DIMM + t];
    float s = v, ss = v * v;
    #pragma unroll
    for (int off = 1; off < 64; off <<= 1) {
        s += __shfl_xor(s, off);
        ss += __shfl_xor(ss, off);
    }
    __shared__ float red[2][4];
    int w = t >> 6, lane = t & 63;
    if (lane == 0) { red[0][w] = s; red[1][w] = ss; }
    __syncthreads();
    s = red[0][0] + red[0][1] + red[0][2] + red[0][3];
    ss = red[1][0] + red[1][1] + red[1][2] + red[1][3];
    float mu = s * (1.0f / DIMM);
    float var = ss * (1.0f / DIMM) - mu * mu;
    float rs = rsqrtf(var + 1e-5f);
    x[row * DIMM + t] = (v - mu) * rs * gamma[t] + beta[t];
}

// ---------------- K2: QKV projection (f32 in, bf16 out; V stored transposed) ----------------
__global__ __launch_bounds__(256) void qkv_kernel(const float* __restrict__ x,
                                                  const float* __restrict__ Wqkv,
                                                  __hip_bfloat16* __restrict__ qb,
                                                  __hip_bfloat16* __restrict__ kb,
                                                  __hip_bfloat16* __restrict__ vtb) {
    __shared__ float xs[16][DIMM];
    int rt = blockIdx.x;
    int cbase = blockIdx.y * 256;
    int tid = threadIdx.x;
    for (int idx = tid; idx < 16 * DIMM; idx += 256) {
        int r = idx >> 8, c = idx & 255;
        xs[r][c] = x[(rt * 16 + r) * DIMM + c];
    }
    __syncthreads();
    int col = cbase + tid;
    float acc[16];
    #pragma unroll
    for (int r = 0; r < 16; ++r) acc[r] = 0.f;
    for (int kk = 0; kk < DIMM; kk += 4) {
        float w0 = Wqkv[(kk + 0) * 1536 + col];
        float w1 = Wqkv[(kk + 1) * 1536 + col];
        float w2 = Wqkv[(kk + 2) * 1536 + col];
        float w3 = Wqkv[(kk + 3) * 1536 + col];
        #pragma unroll
        for (int r = 0; r < 16; ++r) {
            float4 xv = *(const float4*)&xs[r][kk];
            acc[r] += xv.x * w0 + xv.y * w1 + xv.z * w2 + xv.w * w3;
        }
    }
    int part = col / INNERD;     // 0=q,1=k,2=v
    int cc = col % INNERD;
    int h = cc / DH, d = cc % DH;
    #pragma unroll
    for (int r = 0; r < 16; ++r) {
        int gidx = rt * 16 + r;
        int bb = gidx >> 10, nn = gidx & 1023;
        if (part == 0)
            qb[(((bb * HEADS + h) * NN) + nn) * DH + d] = __float2bfloat16(acc[r] * 0.125f);
        else if (part == 1)
            kb[(((bb * HEADS + h) * NN) + nn) * DH + d] = __float2bfloat16(acc[r]);
        else
            vtb[(((bb * HEADS + h) * DH) + d) * NN + nn] = __float2bfloat16(acc[r]);
    }
}

// ---------------- K3: pairwise delta MLP -> md (b,i,j,3) ----------------
__global__ __launch_bounds__(256) void dmlp_kernel(const float* __restrict__ xyz,
                                                   const float* __restrict__ Wp1,
                                                   const float* __restrict__ Wp2,
                                                   const float* __restrict__ Wn1,
                                                   const float* __restrict__ Wn2,
                                                   const float* __restrict__ Wc,
                                                   const float* __restrict__ bc,
                                                   float* __restrict__ md) {
    __shared__ float w_p1[48], w_p2[48], w_n1[48], w_n2[48], w_c[9], b_c[3];
    int tid = threadIdx.x;
    if (tid < 48) { w_p1[tid] = Wp1[tid]; w_n1[tid] = Wn1[tid];
                    w_p2[tid] = Wp2[tid]; w_n2[tid] = Wn2[tid]; }
    if (tid < 9) w_c[tid] = Wc[tid];
    if (tid < 3) b_c[tid] = bc[tid];
    __syncthreads();
    long e = (long)blockIdx.x * 256 + tid;
    int j = (int)(e & (NN - 1));
    long t2 = e >> 10;
    int i = (int)(t2 & (NN - 1));
    int b = (int)(t2 >> 10);
    float d0 = xyz[(b * NN + j) * 3 + 0] - xyz[(b * NN + i) * 3 + 0];
    float d1 = xyz[(b * NN + j) * 3 + 1] - xyz[(b * NN + i) * 3 + 1];
    float d2 = xyz[(b * NN + j) * 3 + 2] - xyz[(b * NN + i) * 3 + 2];

    float p0, p1, p2, n0, n1, n2;
    {
        float r0 = fmaxf(d0, 0.f), r1 = fmaxf(d1, 0.f), r2 = fmaxf(d2, 0.f);
        float a0 = 0.f, a1 = 0.f, a2 = 0.f;
        #pragma unroll
        for (int m = 0; m < 16; ++m) {
            float t = r0 * w_p1[m] + r1 * w_p1[16 + m] + r2 * w_p1[32 + m];
            t = gelu_f(t);
            a0 += t * w_p2[m * 3 + 0];
            a1 += t * w_p2[m * 3 + 1];
            a2 += t * w_p2[m * 3 + 2];
        }
        p0 = leaky_f(a0); p1 = leaky_f(a1); p2 = leaky_f(a2);
    }
    {
        float r0 = fmaxf(-d0, 0.f), r1 = fmaxf(-d1, 0.f), r2 = fmaxf(-d2, 0.f);
        float a0 = 0.f, a1 = 0.f, a2 = 0.f;
        #pragma unroll
        for (int m = 0; m < 16; ++m) {
            float t = r0 * w_n1[m] + r1 * w_n1[16 + m] + r2 * w_n1[32 + m];
            t = gelu_f(t);
            a0 += t * w_n2[m * 3 + 0];
            a1 += t * w_n2[m * 3 + 1];
            a2 += t * w_n2[m * 3 + 2];
        }
        n0 = leaky_f(a0); n1 = leaky_f(a1); n2 = leaky_f(a2);
    }
    float pn0 = p0 * n0, pn1 = p1 * n1, pn2 = p2 * n2;
    float c0 = leaky_f(pn0 * w_c[0] + pn1 * w_c[3] + pn2 * w_c[6] + b_c[0]);
    float c1 = leaky_f(pn0 * w_c[1] + pn1 * w_c[4] + pn2 * w_c[7] + b_c[1]);
    float c2 = leaky_f(pn0 * w_c[2] + pn1 * w_c[5] + pn2 * w_c[8] + b_c[2]);
    long o = e * 3;
    md[o + 0] = c0 * d0;
    md[o + 1] = c1 * d1;
    md[o + 2] = c2 * d2;
}

// ---------------- K4: fused MFMA attention ----------------
// grid (16 i-tiles of 64, 8 heads, 4 batches), block 256 = 4 waves.
// Each wave owns 16 q-rows: wave-local online softmax, MFMA QK^T and PV.
// K/V^T double-buffered in LDS with XOR swizzle (T2); reg-staged prefetch (T14-lite).
__global__ __launch_bounds__(256) void attn_kernel(
    const __hip_bfloat16* __restrict__ q,
    const __hip_bfloat16* __restrict__ kk,
    const __hip_bfloat16* __restrict__ vt,
    const float* __restrict__ md,
    const float* __restrict__ Wsp,
    float* __restrict__ y)
{
    int it = blockIdx.x, h = blockIdx.y, b = blockIdx.z;
    int tid = threadIdx.x;
    int w = tid >> 6, lane = tid & 63;
    int g = lane >> 4, c = lane & 15;

    __shared__ __align__(16) __hip_bfloat16 k_lds[2][64][64];
    __shared__ __align__(16) __hip_bfloat16 v_lds[2][64][64];   // stores V^T tile: [d][j]
    __shared__ __align__(16) __hip_bfloat16 p_lds[4][16][64];   // per-wave P tile

    const __hip_bfloat16* qp = q + ((long)(b * HEADS + h) * NN + it * 64) * DH;
    const __hip_bfloat16* kp = kk + (long)(b * HEADS + h) * NN * DH;
    const __hip_bfloat16* vp = vt + (long)(b * HEADS + h) * DH * NN;

    // Q A-fragments (row = c, k = t2*32 + g*8 + e)
    bf16x8 qa[2];
    #pragma unroll
    for (int t2 = 0; t2 < 2; ++t2)
        qa[t2] = *reinterpret_cast<const bf16x8*>(qp + (w * 16 + c) * DH + t2 * 32 + g * 8);

    // staging: each thread moves 2x16B of K and 2x16B of V^T per tile
    int r0 = tid >> 3;
    int d00 = (tid & 7) * 8;
    int4 kreg[2], vreg[2];

    f32x4 o[4];
    #pragma unroll
    for (int df = 0; df < 4; ++df) { o[df][0] = 0.f; o[df][1] = 0.f; o[df][2] = 0.f; o[df][3] = 0.f; }
    float m_[4] = {-1e30f, -1e30f, -1e30f, -1e30f};
    float l_[4] = {0.f, 0.f, 0.f, 0.f};
    float wdx[4] = {0.f, 0.f, 0.f, 0.f}, wdy[4] = {0.f, 0.f, 0.f, 0.f}, wdz[4] = {0.f, 0.f, 0.f, 0.f};

    // prologue: stage tile 0
    #pragma unroll
    for (int c2 = 0; c2 < 2; ++c2) {
        int r = r0 + c2 * 32;
        kreg[c2] = *reinterpret_cast<const int4*>(kp + (0 * 64 + r) * DH + d00);
        vreg[c2] = *reinterpret_cast<const int4*>(vp + (long)r * NN + 0 * 64 + d00);
    }
    #pragma unroll
    for (int c2 = 0; c2 < 2; ++c2) {
        int r = r0 + c2 * 32;
        int sd = d00 ^ ((r & 7) << 3);
        *reinterpret_cast<int4*>(&k_lds[0][r][sd]) = kreg[c2];
        *reinterpret_cast<int4*>(&v_lds[0][r][sd]) = vreg[c2];
    }
    __syncthreads();

    const float* mdp0 = md + ((long)(b * NN + it * 64 + w * 16 + g * 4) * NN + c) * 3;

    for (int t = 0; t < NT; ++t) {
        int buf = t & 1;
        if (t + 1 < NT) {
            #pragma unroll
            for (int c2 = 0; c2 < 2; ++c2) {
                int r = r0 + c2 * 32;
                kreg[c2] = *reinterpret_cast<const int4*>(kp + ((t + 1) * 64 + r) * DH + d00);
                vreg[c2] = *reinterpret_cast<const int4*>(vp + (long)r * NN + (t + 1) * 64 + d00);
            }
        }

        // QK^T: 4 j-fragments x 2 k-steps
        f32x4 s[4];
        #pragma unroll
        for (int jf = 0; jf < 4; ++jf) {
            f32x4 acc = {0.f, 0.f, 0.f, 0.f};
            int jl = jf * 16 + c;
            int sw = (jl & 7) << 3;
            #pragma unroll
            for (int t2 = 0; t2 < 2; ++t2) {
                bf16x8 bk = *reinterpret_cast<const bf16x8*>(&k_lds[buf][jl][(t2 * 32 + g * 8) ^ sw]);
                acc = __builtin_amdgcn_mfma_f32_16x16x32_bf16(qa[t2], bk, acc, 0, 0, 0);
            }
            s[jf] = acc;
        }

        // online softmax (wave-local; lane owns rows g*4+r, cols jf*16+c)
        float pe[4][4];
        #pragma unroll
        for (int r = 0; r < 4; ++r) {
            float tm = fmaxf(fmaxf(s[0][r], s[1][r]), fmaxf(s[2][r], s[3][r]));
            tm = fmaxf(tm, __shfl_xor(tm, 1));
            tm = fmaxf(tm, __shfl_xor(tm, 2));
            tm = fmaxf(tm, __shfl_xor(tm, 4));
            tm = fmaxf(tm, __shfl_xor(tm, 8));
            float nm = fmaxf(m_[r], tm);
            float corr = __expf(m_[r] - nm);
            m_[r] = nm;
            l_[r] *= corr;
            wdx[r] *= corr; wdy[r] *= corr; wdz[r] *= corr;
            o[0][r] *= corr; o[1][r] *= corr; o[2][r] *= corr; o[3][r] *= corr;
            float ps = 0.f;
            #pragma unroll
            for (int jf = 0; jf < 4; ++jf) {
                float p = __expf(s[jf][r] - nm);
                pe[r][jf] = p;
                ps += p;
            }
            l_[r] += ps;
        }

        // write P tile (bf16, swizzled) to this wave's region
        #pragma unroll
        for (int r = 0; r < 4; ++r) {
            int row = g * 4 + r;
            int sw = (row & 7) << 3;
            #pragma unroll
            for (int jf = 0; jf < 4; ++jf)
                p_lds[w][row][(jf * 16 + c) ^ sw] = __float2bfloat16(pe[r][jf]);
        }
        asm volatile("s_waitcnt lgkmcnt(0)" ::: "memory");

        // wdelta accumulation in (row, col-partial) domain
        #pragma unroll
        for (int r = 0; r < 4; ++r) {
            const float* mp = mdp0 + (long)r * (NN * 3) + t * 192;
            #pragma unroll
            for (int jf = 0; jf < 4; ++jf) {
                float m0 = mp[jf * 48 + 0];
                float m1 = mp[jf * 48 + 1];
                float m2 = mp[jf * 48 + 2];
                wdx[r] += pe[r][jf] * m0;
                wdy[r] += pe[r][jf] * m1;
                wdz[r] += pe[r][jf] * m2;
            }
        }

        // PV: O[16 x 64] += P[16 x 64] @ V[64 x 64]
        #pragma unroll
        for (int t2 = 0; t2 < 2; ++t2) {
            int swp = (c & 7) << 3;
            bf16x8 pa = *reinterpret_cast<const bf16x8*>(&p_lds[w][c][(t2 * 32 + g * 8) ^ swp]);
            #pragma unroll
            for (int df = 0; df < 4; ++df) {
                int dl = df * 16 + c;
                int swv = (dl & 7) << 3;
                bf16x8 bv = *reinterpret_cast<const bf16x8*>(&v_lds[buf][dl][(t2 * 32 + g * 8) ^ swv]);
                o[df] = __builtin_amdgcn_mfma_f32_16x16x32_bf16(pa, bv, o[df], 0, 0, 0);
            }
        }

        // write next tile into the other buffer (safe: everyone left it last iter)
        if (t + 1 < NT) {
            #pragma unroll
            for (int c2 = 0; c2 < 2; ++c2) {
                int r = r0 + c2 * 32;
                int sd = d00 ^ ((r & 7) << 3);
                *reinterpret_cast<int4*>(&k_lds[buf ^ 1][r][sd]) = kreg[c2];
                *reinterpret_cast<int4*>(&v_lds[buf ^ 1][r][sd]) = vreg[c2];
            }
        }
        __syncthreads();
    }

    // epilogue: reduce l and wdelta over the 16 j-lanes, normalize, add disp, store
    #pragma unroll
    for (int r = 0; r < 4; ++r) {
        float lv = l_[r];
        lv += __shfl_xor(lv, 1); lv += __shfl_xor(lv, 2);
        lv += __shfl_xor(lv, 4); lv += __shfl_xor(lv, 8);
        float w0 = wdx[r], w1 = wdy[r], w2 = wdz[r];
        w0 += __shfl_xor(w0, 1); w0 += __shfl_xor(w0, 2); w0 += __shfl_xor(w0, 4); w0 += __shfl_xor(w0, 8);
        w1 += __shfl_xor(w1, 1); w1 += __shfl_xor(w1, 2); w1 += __shfl_xor(w1, 4); w1 += __shfl_xor(w1, 8);
        w2 += __shfl_xor(w2, 1); w2 += __shfl_xor(w2, 2); w2 += __shfl_xor(w2, 4); w2 += __shfl_xor(w2, 8);
        float inv = 1.0f / lv;
        w0 *= inv; w1 *= inv; w2 *= inv;
        int row = g * 4 + r;
        long ig = (long)b * NN + it * 64 + w * 16 + row;
        float* yp = y + ig * INNERD + h * DH;
        #pragma unroll
        for (int df = 0; df < 4; ++df) {
            int d = df * 16 + c;
            float disp = w0 * Wsp[d] + w1 * Wsp[64 + d] + w2 * Wsp[128 + d];
            yp[d] = o[df][r] * inv + disp;
        }
    }
}

// ---------------- K5: output projection + GELU + residual ----------------
__global__ __launch_bounds__(256) void out_kernel(const float* __restrict__ y,
                                                  const float* __restrict__ Wout,
                                                  const float* __restrict__ bout,
                                                  const float* __restrict__ feat,
                                                  float* __restrict__ out) {
    __shared__ float ys[8][INNERD];
    int rt = blockIdx.x;
    int tid = threadIdx.x;
    for (int idx = tid; idx < 8 * INNERD; idx += 256) {
        int r = idx >> 9, c = idx & 511;
        ys[r][c] = y[((long)rt * 8 + r) * INNERD + c];
    }
    __syncthreads();
    float acc[8] = {};
    for (int kk = 0; kk < INNERD; kk += 4) {
        float w0 = Wout[(kk + 0) * DIMM + tid];
        float w1 = Wout[(kk + 1) * DIMM + tid];
        float w2 = Wout[(kk + 2) * DIMM + tid];
        float w3 = Wout[(kk + 3) * DIMM + tid];
        #pragma unroll
        for (int r = 0; r < 8; ++r) {
            float4 yv = *(const float4*)&ys[r][kk];
            acc[r] += yv.x * w0 + yv.y * w1 + yv.z * w2 + yv.w * w3;
        }
    }
    float bo = bout[tid];
    #pragma unroll
    for (int r = 0; r < 8; ++r) {
        long gidx = (long)rt * 8 + r;
        float val = gelu_f(acc[r] + bo);
        out[gidx * DIMM + tid] = val + feat[gidx * DIMM + tid];
    }
}

extern "C" void kernel_launch(void* const* d_in, const int* in_sizes, int n_in,
                              void* d_out, int out_size, void* d_ws, size_t ws_size,
                              hipStream_t stream) {
    const float* xyzs  = (const float*)d_in[0];
    const float* feat  = (const float*)d_in[1];
    const float* gamma = (const float*)d_in[2];
    const float* beta  = (const float*)d_in[3];
    const float* Wqkv  = (const float*)d_in[4];
    const float* Wp1   = (const float*)d_in[5];
    const float* Wp2   = (const float*)d_in[6];
    const float* Wn1   = (const float*)d_in[7];
    const float* Wn2   = (const float*)d_in[8];
    const float* Wc    = (const float*)d_in[9];
    const float* bc    = (const float*)d_in[10];
    const float* Wsp   = (const float*)d_in[11];
    const float* Wout  = (const float*)d_in[12];
    const float* bout  = (const float*)d_in[13];
    float* out = (float*)d_out;

    // workspace layout: x (1M f32) | qb,kb,vtb (2M bf16 each) | y (2M f32) | md (12M f32)
    float* x = (float*)d_ws;
    __hip_bfloat16* qb  = (__hip_bfloat16*)(x + 1048576);
    __hip_bfloat16* kb  = qb + 2097152;
    __hip_bfloat16* vtb = kb + 2097152;
    float* y  = (float*)(vtb + 2097152);
    float* md = y + 2097152;

    ln_kernel<<<4096, 256, 0, stream>>>(feat, gamma, beta, x);
    qkv_kernel<<<dim3(256, 6), 256, 0, stream>>>(x, Wqkv, qb, kb, vtb);
    dmlp_kernel<<<16384, 256, 0, stream>>>(xyzs, Wp1, Wp2, Wn1, Wn2, Wc, bc, md);
    attn_kernel<<<dim3(16, HEADS, BB), 256, 0, stream>>>(qb, kb, vtb, md, Wsp, y);
    out_kernel<<<512, 256, 0, stream>>>(y, Wout, bout, feat, out);
}

// Round 3
// 310.571 us; speedup vs baseline: 5.2091x; 1.1863x over previous
//
#include <hip/hip_runtime.h>
#include <hip/hip_bf16.h>
#include <math.h>

#define BB 4
#define NN 1024
#define DIMM 256
#define HEADS 8
#define DH 64
#define INNERD 512
#define NT 16
#define MDPLANE 4194304   // B*N*N

typedef __bf16 bf16x8 __attribute__((ext_vector_type(8)));
typedef float f32x4 __attribute__((ext_vector_type(4)));

// Fast exact-GELU: Abramowitz-Stegun 7.1.26 erf approx (|err| < 1.5e-7)
__device__ __forceinline__ float fast_gelu(float x) {
    float z = fabsf(x) * 0.70710678118654752f;
    float t = __fdividef(1.0f, fmaf(0.3275911f, z, 1.0f));
    float poly = t * fmaf(t, fmaf(t, fmaf(t, fmaf(t, 1.061405429f, -1.453152027f),
                                          1.421413741f), -0.284496736f), 0.254829592f);
    float E = __expf(-z * z);
    float erf_abs = fmaf(-poly, E, 1.0f);          // erf(|x|/sqrt2)
    float erf_s = copysignf(erf_abs, x);
    float hx = 0.5f * x;
    return fmaf(hx, erf_s, hx);
}
__device__ __forceinline__ float leaky_f(float x) {
    return fmaxf(x, 0.01f * x);
}

// ---------------- K1: LayerNorm ----------------
__global__ __launch_bounds__(256) void ln_kernel(const float* __restrict__ feat,
                                                 const float* __restrict__ gamma,
                                                 const float* __restrict__ beta,
                                                 float* __restrict__ x) {
    int row = blockIdx.x;
    int t = threadIdx.x;
    float v = feat[row * DIMM + t];
    float s = v, ss = v * v;
    #pragma unroll
    for (int off = 1; off < 64; off <<= 1) {
        s += __shfl_xor(s, off);
        ss += __shfl_xor(ss, off);
    }
    __shared__ float red[2][4];
    int w = t >> 6, lane = t & 63;
    if (lane == 0) { red[0][w] = s; red[1][w] = ss; }
    __syncthreads();
    s = red[0][0] + red[0][1] + red[0][2] + red[0][3];
    ss = red[1][0] + red[1][1] + red[1][2] + red[1][3];
    float mu = s * (1.0f / DIMM);
    float var = ss * (1.0f / DIMM) - mu * mu;
    float rs = rsqrtf(var + 1e-5f);
    x[row * DIMM + t] = (v - mu) * rs * gamma[t] + beta[t];
}

// ---------------- K2: QKV projection (f32 in, bf16 out; V stored transposed) ----------------
__global__ __launch_bounds__(256) void qkv_kernel(const float* __restrict__ x,
                                                  const float* __restrict__ Wqkv,
                                                  __hip_bfloat16* __restrict__ qb,
                                                  __hip_bfloat16* __restrict__ kb,
                                                  __hip_bfloat16* __restrict__ vtb) {
    __shared__ float xs[16][DIMM];
    int rt = blockIdx.x;
    int cbase = blockIdx.y * 256;
    int tid = threadIdx.x;
    for (int idx = tid; idx < 16 * DIMM; idx += 256) {
        int r = idx >> 8, c = idx & 255;
        xs[r][c] = x[(rt * 16 + r) * DIMM + c];
    }
    __syncthreads();
    int col = cbase + tid;
    float acc[16];
    #pragma unroll
    for (int r = 0; r < 16; ++r) acc[r] = 0.f;
    for (int kk = 0; kk < DIMM; kk += 4) {
        float w0 = Wqkv[(kk + 0) * 1536 + col];
        float w1 = Wqkv[(kk + 1) * 1536 + col];
        float w2 = Wqkv[(kk + 2) * 1536 + col];
        float w3 = Wqkv[(kk + 3) * 1536 + col];
        #pragma unroll
        for (int r = 0; r < 16; ++r) {
            float4 xv = *(const float4*)&xs[r][kk];
            acc[r] += xv.x * w0 + xv.y * w1 + xv.z * w2 + xv.w * w3;
        }
    }
    int part = col / INNERD;     // 0=q,1=k,2=v
    int cc = col % INNERD;
    int h = cc / DH, d = cc % DH;
    #pragma unroll
    for (int r = 0; r < 16; ++r) {
        int gidx = rt * 16 + r;
        int bb = gidx >> 10, nn = gidx & 1023;
        if (part == 0)
            qb[(((bb * HEADS + h) * NN) + nn) * DH + d] = __float2bfloat16(acc[r] * 0.125f);
        else if (part == 1)
            kb[(((bb * HEADS + h) * NN) + nn) * DH + d] = __float2bfloat16(acc[r]);
        else
            vtb[(((bb * HEADS + h) * DH) + d) * NN + nn] = __float2bfloat16(acc[r]);
    }
}

// ---------------- K3: pairwise delta MLP -> planar md[3][b,i,j] ----------------
// 2 elements per thread (same i): weight loads amortized, no LDS, no barriers.
__global__ __launch_bounds__(256) void dmlp_kernel(const float* __restrict__ xyz,
                                                   const float* __restrict__ Wp1,
                                                   const float* __restrict__ Wp2,
                                                   const float* __restrict__ Wn1,
                                                   const float* __restrict__ Wn2,
                                                   const float* __restrict__ Wc,
                                                   const float* __restrict__ bc,
                                                   float* __restrict__ md) {
    int tid = threadIdx.x;
    int half = blockIdx.x & 1;
    int bi = blockIdx.x >> 1;           // b*N + i  (uniform per block)
    int b = bi >> 10;
    int i = bi & 1023;
    int j0 = half * 512 + tid;
    int j1 = j0 + 256;

    float xi0 = xyz[bi * 3 + 0], xi1 = xyz[bi * 3 + 1], xi2 = xyz[bi * 3 + 2];
    const float* xj = xyz + (long)b * NN * 3;
    float dA0 = xj[j0 * 3 + 0] - xi0, dA1 = xj[j0 * 3 + 1] - xi1, dA2 = xj[j0 * 3 + 2] - xi2;
    float dB0 = xj[j1 * 3 + 0] - xi0, dB1 = xj[j1 * 3 + 1] - xi1, dB2 = xj[j1 * 3 + 2] - xi2;

    float pA0, pA1, pA2, pB0, pB1, pB2;
    float nA0, nA1, nA2, nB0, nB1, nB2;
    {   // pos branch
        float rA0 = fmaxf(dA0, 0.f), rA1 = fmaxf(dA1, 0.f), rA2 = fmaxf(dA2, 0.f);
        float rB0 = fmaxf(dB0, 0.f), rB1 = fmaxf(dB1, 0.f), rB2 = fmaxf(dB2, 0.f);
        float aA0 = 0.f, aA1 = 0.f, aA2 = 0.f, aB0 = 0.f, aB1 = 0.f, aB2 = 0.f;
        #pragma unroll
        for (int m = 0; m < 16; ++m) {
            float w0 = Wp1[m], w1 = Wp1[16 + m], w2 = Wp1[32 + m];
            float u0 = Wp2[3 * m + 0], u1 = Wp2[3 * m + 1], u2 = Wp2[3 * m + 2];
            float tA = fmaf(rA0, w0, fmaf(rA1, w1, rA2 * w2));
            float tB = fmaf(rB0, w0, fmaf(rB1, w1, rB2 * w2));
            tA = fast_gelu(tA);
            tB = fast_gelu(tB);
            aA0 = fmaf(tA, u0, aA0); aA1 = fmaf(tA, u1, aA1); aA2 = fmaf(tA, u2, aA2);
            aB0 = fmaf(tB, u0, aB0); aB1 = fmaf(tB, u1, aB1); aB2 = fmaf(tB, u2, aB2);
        }
        pA0 = leaky_f(aA0); pA1 = leaky_f(aA1); pA2 = leaky_f(aA2);
        pB0 = leaky_f(aB0); pB1 = leaky_f(aB1); pB2 = leaky_f(aB2);
    }
    {   // neg branch
        float rA0 = fmaxf(-dA0, 0.f), rA1 = fmaxf(-dA1, 0.f), rA2 = fmaxf(-dA2, 0.f);
        float rB0 = fmaxf(-dB0, 0.f), rB1 = fmaxf(-dB1, 0.f), rB2 = fmaxf(-dB2, 0.f);
        float aA0 = 0.f, aA1 = 0.f, aA2 = 0.f, aB0 = 0.f, aB1 = 0.f, aB2 = 0.f;
        #pragma unroll
        for (int m = 0; m < 16; ++m) {
            float w0 = Wn1[m], w1 = Wn1[16 + m], w2 = Wn1[32 + m];
            float u0 = Wn2[3 * m + 0], u1 = Wn2[3 * m + 1], u2 = Wn2[3 * m + 2];
            float tA = fmaf(rA0, w0, fmaf(rA1, w1, rA2 * w2));
            float tB = fmaf(rB0, w0, fmaf(rB1, w1, rB2 * w2));
            tA = fast_gelu(tA);
            tB = fast_gelu(tB);
            aA0 = fmaf(tA, u0, aA0); aA1 = fmaf(tA, u1, aA1); aA2 = fmaf(tA, u2, aA2);
            aB0 = fmaf(tB, u0, aB0); aB1 = fmaf(tB, u1, aB1); aB2 = fmaf(tB, u2, aB2);
        }
        nA0 = leaky_f(aA0); nA1 = leaky_f(aA1); nA2 = leaky_f(aA2);
        nB0 = leaky_f(aB0); nB1 = leaky_f(aB1); nB2 = leaky_f(aB2);
    }
    float c00 = Wc[0], c01 = Wc[1], c02 = Wc[2];
    float c10 = Wc[3], c11 = Wc[4], c12 = Wc[5];
    float c20 = Wc[6], c21 = Wc[7], c22 = Wc[8];
    float b0 = bc[0], b1 = bc[1], b2 = bc[2];

    float qA0 = pA0 * nA0, qA1 = pA1 * nA1, qA2 = pA2 * nA2;
    float qB0 = pB0 * nB0, qB1 = pB1 * nB1, qB2 = pB2 * nB2;
    float cA0 = leaky_f(fmaf(qA0, c00, fmaf(qA1, c10, fmaf(qA2, c20, b0))));
    float cA1 = leaky_f(fmaf(qA0, c01, fmaf(qA1, c11, fmaf(qA2, c21, b1))));
    float cA2 = leaky_f(fmaf(qA0, c02, fmaf(qA1, c12, fmaf(qA2, c22, b2))));
    float cB0 = leaky_f(fmaf(qB0, c00, fmaf(qB1, c10, fmaf(qB2, c20, b0))));
    float cB1 = leaky_f(fmaf(qB0, c01, fmaf(qB1, c11, fmaf(qB2, c21, b1))));
    float cB2 = leaky_f(fmaf(qB0, c02, fmaf(qB1, c12, fmaf(qB2, c22, b2))));

    long base = (long)bi * NN;
    md[base + j0]               = cA0 * dA0;
    md[base + j1]               = cB0 * dB0;
    md[MDPLANE + base + j0]     = cA1 * dA1;
    md[MDPLANE + base + j1]     = cB1 * dB1;
    md[2 * MDPLANE + base + j0] = cA2 * dA2;
    md[2 * MDPLANE + base + j1] = cB2 * dB2;
}

// ---------------- K4: fused MFMA attention ----------------
__global__ __launch_bounds__(256) void attn_kernel(
    const __hip_bfloat16* __restrict__ q,
    const __hip_bfloat16* __restrict__ kk,
    const __hip_bfloat16* __restrict__ vt,
    const float* __restrict__ md,
    const float* __restrict__ Wsp,
    float* __restrict__ y)
{
    int it = blockIdx.x, h = blockIdx.y, b = blockIdx.z;
    int tid = threadIdx.x;
    int w = tid >> 6, lane = tid & 63;
    int g = lane >> 4, c = lane & 15;

    __shared__ __align__(16) __hip_bfloat16 k_lds[2][64][64];
    __shared__ __align__(16) __hip_bfloat16 v_lds[2][64][64];   // V^T tile: [d][j]
    __shared__ __align__(16) __hip_bfloat16 p_lds[4][16][64];

    const __hip_bfloat16* qp = q + ((long)(b * HEADS + h) * NN + it * 64) * DH;
    const __hip_bfloat16* kp = kk + (long)(b * HEADS + h) * NN * DH;
    const __hip_bfloat16* vp = vt + (long)(b * HEADS + h) * DH * NN;

    bf16x8 qa[2];
    #pragma unroll
    for (int t2 = 0; t2 < 2; ++t2)
        qa[t2] = *reinterpret_cast<const bf16x8*>(qp + (w * 16 + c) * DH + t2 * 32 + g * 8);

    int r0 = tid >> 3;
    int d00 = (tid & 7) * 8;
    int4 kreg[2], vreg[2];

    f32x4 o[4];
    #pragma unroll
    for (int df = 0; df < 4; ++df) { o[df][0] = 0.f; o[df][1] = 0.f; o[df][2] = 0.f; o[df][3] = 0.f; }
    float m_[4] = {-1e30f, -1e30f, -1e30f, -1e30f};
    float l_[4] = {0.f, 0.f, 0.f, 0.f};
    float wdx[4] = {0.f, 0.f, 0.f, 0.f}, wdy[4] = {0.f, 0.f, 0.f, 0.f}, wdz[4] = {0.f, 0.f, 0.f, 0.f};

    #pragma unroll
    for (int c2 = 0; c2 < 2; ++c2) {
        int r = r0 + c2 * 32;
        kreg[c2] = *reinterpret_cast<const int4*>(kp + (0 * 64 + r) * DH + d00);
        vreg[c2] = *reinterpret_cast<const int4*>(vp + (long)r * NN + 0 * 64 + d00);
    }
    #pragma unroll
    for (int c2 = 0; c2 < 2; ++c2) {
        int r = r0 + c2 * 32;
        int sd = d00 ^ ((r & 7) << 3);
        *reinterpret_cast<int4*>(&k_lds[0][r][sd]) = kreg[c2];
        *reinterpret_cast<int4*>(&v_lds[0][r][sd]) = vreg[c2];
    }
    __syncthreads();

    const float* md0 = md;
    const float* md1 = md + MDPLANE;
    const float* md2 = md + 2 * MDPLANE;
    long mdrow = (long)(b * NN + it * 64 + w * 16 + g * 4) * NN + c;

    for (int t = 0; t < NT; ++t) {
        int buf = t & 1;
        if (t + 1 < NT) {
            #pragma unroll
            for (int c2 = 0; c2 < 2; ++c2) {
                int r = r0 + c2 * 32;
                kreg[c2] = *reinterpret_cast<const int4*>(kp + ((t + 1) * 64 + r) * DH + d00);
                vreg[c2] = *reinterpret_cast<const int4*>(vp + (long)r * NN + (t + 1) * 64 + d00);
            }
        }

        f32x4 s[4];
        #pragma unroll
        for (int jf = 0; jf < 4; ++jf) {
            f32x4 acc = {0.f, 0.f, 0.f, 0.f};
            int jl = jf * 16 + c;
            int sw = (jl & 7) << 3;
            #pragma unroll
            for (int t2 = 0; t2 < 2; ++t2) {
                bf16x8 bk = *reinterpret_cast<const bf16x8*>(&k_lds[buf][jl][(t2 * 32 + g * 8) ^ sw]);
                acc = __builtin_amdgcn_mfma_f32_16x16x32_bf16(qa[t2], bk, acc, 0, 0, 0);
            }
            s[jf] = acc;
        }

        float pe[4][4];
        #pragma unroll
        for (int r = 0; r < 4; ++r) {
            float tm = fmaxf(fmaxf(s[0][r], s[1][r]), fmaxf(s[2][r], s[3][r]));
            tm = fmaxf(tm, __shfl_xor(tm, 1));
            tm = fmaxf(tm, __shfl_xor(tm, 2));
            tm = fmaxf(tm, __shfl_xor(tm, 4));
            tm = fmaxf(tm, __shfl_xor(tm, 8));
            float nm = fmaxf(m_[r], tm);
            float corr = __expf(m_[r] - nm);
            m_[r] = nm;
            l_[r] *= corr;
            wdx[r] *= corr; wdy[r] *= corr; wdz[r] *= corr;
            o[0][r] *= corr; o[1][r] *= corr; o[2][r] *= corr; o[3][r] *= corr;
            float ps = 0.f;
            #pragma unroll
            for (int jf = 0; jf < 4; ++jf) {
                float p = __expf(s[jf][r] - nm);
                pe[r][jf] = p;
                ps += p;
            }
            l_[r] += ps;
        }

        #pragma unroll
        for (int r = 0; r < 4; ++r) {
            int row = g * 4 + r;
            int sw = (row & 7) << 3;
            #pragma unroll
            for (int jf = 0; jf < 4; ++jf)
                p_lds[w][row][(jf * 16 + c) ^ sw] = __float2bfloat16(pe[r][jf]);
        }
        asm volatile("s_waitcnt lgkmcnt(0)" ::: "memory");

        #pragma unroll
        for (int r = 0; r < 4; ++r) {
            long off = mdrow + (long)r * NN + t * 64;
            #pragma unroll
            for (int jf = 0; jf < 4; ++jf) {
                float m0 = md0[off + jf * 16];
                float m1 = md1[off + jf * 16];
                float m2 = md2[off + jf * 16];
                wdx[r] = fmaf(pe[r][jf], m0, wdx[r]);
                wdy[r] = fmaf(pe[r][jf], m1, wdy[r]);
                wdz[r] = fmaf(pe[r][jf], m2, wdz[r]);
            }
        }

        #pragma unroll
        for (int t2 = 0; t2 < 2; ++t2) {
            int swp = (c & 7) << 3;
            bf16x8 pa = *reinterpret_cast<const bf16x8*>(&p_lds[w][c][(t2 * 32 + g * 8) ^ swp]);
            #pragma unroll
            for (int df = 0; df < 4; ++df) {
                int dl = df * 16 + c;
                int swv = (dl & 7) << 3;
                bf16x8 bv = *reinterpret_cast<const bf16x8*>(&v_lds[buf][dl][(t2 * 32 + g * 8) ^ swv]);
                o[df] = __builtin_amdgcn_mfma_f32_16x16x32_bf16(pa, bv, o[df], 0, 0, 0);
            }
        }

        if (t + 1 < NT) {
            #pragma unroll
            for (int c2 = 0; c2 < 2; ++c2) {
                int r = r0 + c2 * 32;
                int sd = d00 ^ ((r & 7) << 3);
                *reinterpret_cast<int4*>(&k_lds[buf ^ 1][r][sd]) = kreg[c2];
                *reinterpret_cast<int4*>(&v_lds[buf ^ 1][r][sd]) = vreg[c2];
            }
        }
        __syncthreads();
    }

    #pragma unroll
    for (int r = 0; r < 4; ++r) {
        float lv = l_[r];
        lv += __shfl_xor(lv, 1); lv += __shfl_xor(lv, 2);
        lv += __shfl_xor(lv, 4); lv += __shfl_xor(lv, 8);
        float w0 = wdx[r], w1 = wdy[r], w2 = wdz[r];
        w0 += __shfl_xor(w0, 1); w0 += __shfl_xor(w0, 2); w0 += __shfl_xor(w0, 4); w0 += __shfl_xor(w0, 8);
        w1 += __shfl_xor(w1, 1); w1 += __shfl_xor(w1, 2); w1 += __shfl_xor(w1, 4); w1 += __shfl_xor(w1, 8);
        w2 += __shfl_xor(w2, 1); w2 += __shfl_xor(w2, 2); w2 += __shfl_xor(w2, 4); w2 += __shfl_xor(w2, 8);
        float inv = 1.0f / lv;
        w0 *= inv; w1 *= inv; w2 *= inv;
        int row = g * 4 + r;
        long ig = (long)b * NN + it * 64 + w * 16 + row;
        float* yp = y + ig * INNERD + h * DH;
        #pragma unroll
        for (int df = 0; df < 4; ++df) {
            int d = df * 16 + c;
            float disp = w0 * Wsp[d] + w1 * Wsp[64 + d] + w2 * Wsp[128 + d];
            yp[d] = o[df][r] * inv + disp;
        }
    }
}

// ---------------- K5: output projection + GELU + residual ----------------
__global__ __launch_bounds__(256) void out_kernel(const float* __restrict__ y,
                                                  const float* __restrict__ Wout,
                                                  const float* __restrict__ bout,
                                                  const float* __restrict__ feat,
                                                  float* __restrict__ out) {
    __shared__ float ys[8][INNERD];
    int rt = blockIdx.x;
    int tid = threadIdx.x;
    for (int idx = tid; idx < 8 * INNERD; idx += 256) {
        int r = idx >> 9, c = idx & 511;
        ys[r][c] = y[((long)rt * 8 + r) * INNERD + c];
    }
    __syncthreads();
    float acc[8] = {};
    for (int kk = 0; kk < INNERD; kk += 4) {
        float w0 = Wout[(kk + 0) * DIMM + tid];
        float w1 = Wout[(kk + 1) * DIMM + tid];
        float w2 = Wout[(kk + 2) * DIMM + tid];
        float w3 = Wout[(kk + 3) * DIMM + tid];
        #pragma unroll
        for (int r = 0; r < 8; ++r) {
            float4 yv = *(const float4*)&ys[r][kk];
            acc[r] += yv.x * w0 + yv.y * w1 + yv.z * w2 + yv.w * w3;
        }
    }
    float bo = bout[tid];
    #pragma unroll
    for (int r = 0; r < 8; ++r) {
        long gidx = (long)rt * 8 + r;
        float val = fast_gelu(acc[r] + bo);
        out[gidx * DIMM + tid] = val + feat[gidx * DIMM + tid];
    }
}

extern "C" void kernel_launch(void* const* d_in, const int* in_sizes, int n_in,
                              void* d_out, int out_size, void* d_ws, size_t ws_size,
                              hipStream_t stream) {
    const float* xyzs  = (const float*)d_in[0];
    const float* feat  = (const float*)d_in[1];
    const float* gamma = (const float*)d_in[2];
    const float* beta  = (const float*)d_in[3];
    const float* Wqkv  = (const float*)d_in[4];
    const float* Wp1   = (const float*)d_in[5];
    const float* Wp2   = (const float*)d_in[6];
    const float* Wn1   = (const float*)d_in[7];
    const float* Wn2   = (const float*)d_in[8];
    const float* Wc    = (const float*)d_in[9];
    const float* bc    = (const float*)d_in[10];
    const float* Wsp   = (const float*)d_in[11];
    const float* Wout  = (const float*)d_in[12];
    const float* bout  = (const float*)d_in[13];
    float* out = (float*)d_out;

    // workspace: x (1M f32) | qb,kb,vtb (2M bf16 each) | y (2M f32) | md planar (3 x 4M f32)
    float* x = (float*)d_ws;
    __hip_bfloat16* qb  = (__hip_bfloat16*)(x + 1048576);
    __hip_bfloat16* kb  = qb + 2097152;
    __hip_bfloat16* vtb = kb + 2097152;
    float* y  = (float*)(vtb + 2097152);
    float* md = y + 2097152;

    ln_kernel<<<4096, 256, 0, stream>>>(feat, gamma, beta, x);
    qkv_kernel<<<dim3(256, 6), 256, 0, stream>>>(x, Wqkv, qb, kb, vtb);
    dmlp_kernel<<<8192, 256, 0, stream>>>(xyzs, Wp1, Wp2, Wn1, Wn2, Wc, bc, md);
    attn_kernel<<<dim3(16, HEADS, BB), 256, 0, stream>>>(qb, kb, vtb, md, Wsp, y);
    out_kernel<<<512, 256, 0, stream>>>(y, Wout, bout, feat, out);
}

// Round 4
// 237.867 us; speedup vs baseline: 6.8013x; 1.3056x over previous
//
#include <hip/hip_runtime.h>
#include <hip/hip_bf16.h>
#include <math.h>

#define BB 4
#define NN 1024
#define DIMM 256
#define HEADS 8
#define DH 64
#define INNERD 512
#define NT 16
#define MDPLANE 4194304   // B*N*N

typedef __bf16 bf16x8 __attribute__((ext_vector_type(8)));
typedef float f32x4 __attribute__((ext_vector_type(4)));

// Trans-free GELU: clamp to [-3,3] + degree-9 odd poly for erf(x/sqrt2).
// Coeffs from Newton interpolation at Chebyshev nodes on u=x^2 in [0,9];
// verified |erf err| <= 9e-4 -> |gelu err| <= ~3e-3 (incl. clamp tails).
__device__ __forceinline__ float gelu_poly(float x) {
    float xc = fminf(fmaxf(x, -3.0f), 3.0f);
    float u = xc * xc;
    float f = fmaf(u, fmaf(u, fmaf(u, fmaf(u, 4.4413e-5f, -1.33195e-3f),
                                   1.70980e-2f), -1.299964e-1f), 7.9734583e-1f);
    float E = xc * f;                 // ~erf(xc/sqrt2)
    float hx = 0.5f * xc;
    float g = fmaf(hx, E, hx);        // gelu(xc)
    return g + fmaxf(x - 3.0f, 0.0f); // linear continuation for x>3
}
__device__ __forceinline__ float leaky_f(float x) {
    return fmaxf(x, 0.01f * x);
}

// ---------------- K1: LayerNorm ----------------
__global__ __launch_bounds__(256) void ln_kernel(const float* __restrict__ feat,
                                                 const float* __restrict__ gamma,
                                                 const float* __restrict__ beta,
                                                 float* __restrict__ x) {
    int row = blockIdx.x;
    int t = threadIdx.x;
    float v = feat[row * DIMM + t];
    float s = v, ss = v * v;
    #pragma unroll
    for (int off = 1; off < 64; off <<= 1) {
        s += __shfl_xor(s, off);
        ss += __shfl_xor(ss, off);
    }
    __shared__ float red[2][4];
    int w = t >> 6, lane = t & 63;
    if (lane == 0) { red[0][w] = s; red[1][w] = ss; }
    __syncthreads();
    s = red[0][0] + red[0][1] + red[0][2] + red[0][3];
    ss = red[1][0] + red[1][1] + red[1][2] + red[1][3];
    float mu = s * (1.0f / DIMM);
    float var = ss * (1.0f / DIMM) - mu * mu;
    float rs = rsqrtf(var + 1e-5f);
    x[row * DIMM + t] = (v - mu) * rs * gamma[t] + beta[t];
}

// ---------------- K2: QKV projection (f32 in, bf16 out; V stored transposed) ----------------
__global__ __launch_bounds__(256) void qkv_kernel(const float* __restrict__ x,
                                                  const float* __restrict__ Wqkv,
                                                  __hip_bfloat16* __restrict__ qb,
                                                  __hip_bfloat16* __restrict__ kb,
                                                  __hip_bfloat16* __restrict__ vtb) {
    __shared__ float xs[16][DIMM];
    int rt = blockIdx.x;
    int cbase = blockIdx.y * 256;
    int tid = threadIdx.x;
    for (int idx = tid; idx < 16 * DIMM; idx += 256) {
        int r = idx >> 8, c = idx & 255;
        xs[r][c] = x[(rt * 16 + r) * DIMM + c];
    }
    __syncthreads();
    int col = cbase + tid;
    float acc[16];
    #pragma unroll
    for (int r = 0; r < 16; ++r) acc[r] = 0.f;
    for (int kk = 0; kk < DIMM; kk += 4) {
        float w0 = Wqkv[(kk + 0) * 1536 + col];
        float w1 = Wqkv[(kk + 1) * 1536 + col];
        float w2 = Wqkv[(kk + 2) * 1536 + col];
        float w3 = Wqkv[(kk + 3) * 1536 + col];
        #pragma unroll
        for (int r = 0; r < 16; ++r) {
            float4 xv = *(const float4*)&xs[r][kk];
            acc[r] += xv.x * w0 + xv.y * w1 + xv.z * w2 + xv.w * w3;
        }
    }
    int part = col / INNERD;     // 0=q,1=k,2=v
    int cc = col % INNERD;
    int h = cc / DH, d = cc % DH;
    #pragma unroll
    for (int r = 0; r < 16; ++r) {
        int gidx = rt * 16 + r;
        int bb = gidx >> 10, nn = gidx & 1023;
        if (part == 0)
            qb[(((bb * HEADS + h) * NN) + nn) * DH + d] = __float2bfloat16(acc[r] * 0.125f);
        else if (part == 1)
            kb[(((bb * HEADS + h) * NN) + nn) * DH + d] = __float2bfloat16(acc[r]);
        else
            vtb[(((bb * HEADS + h) * DH) + d) * NN + nn] = __float2bfloat16(acc[r]);
    }
}

// ---------------- K3: pairwise delta MLP -> planar md[3][b,i,j] ----------------
// One block per (b,i) row; 4 pairs per thread for ILP; trans-free GELU.
__global__ __launch_bounds__(256) void dmlp_kernel(const float* __restrict__ xyz,
                                                   const float* __restrict__ Wp1,
                                                   const float* __restrict__ Wp2,
                                                   const float* __restrict__ Wn1,
                                                   const float* __restrict__ Wn2,
                                                   const float* __restrict__ Wc,
                                                   const float* __restrict__ bc,
                                                   float* __restrict__ md) {
    int tid = threadIdx.x;
    int bi = blockIdx.x;            // b*N + i
    int b = bi >> 10;
    const float* xj = xyz + (long)b * NN * 3;
    float xi0 = xyz[bi * 3 + 0], xi1 = xyz[bi * 3 + 1], xi2 = xyz[bi * 3 + 2];

    float d0[4], d1[4], d2[4];
    #pragma unroll
    for (int p = 0; p < 4; ++p) {
        int j = tid + p * 256;
        d0[p] = xj[j * 3 + 0] - xi0;
        d1[p] = xj[j * 3 + 1] - xi1;
        d2[p] = xj[j * 3 + 2] - xi2;
    }

    float pp0[4], pp1[4], pp2[4], nv0[4], nv1[4], nv2[4];
    {   // pos branch
        float r0[4], r1[4], r2[4];
        float a0[4] = {}, a1[4] = {}, a2[4] = {};
        #pragma unroll
        for (int p = 0; p < 4; ++p) {
            r0[p] = fmaxf(d0[p], 0.f); r1[p] = fmaxf(d1[p], 0.f); r2[p] = fmaxf(d2[p], 0.f);
        }
        #pragma unroll
        for (int m = 0; m < 16; ++m) {
            float w0 = Wp1[m], w1 = Wp1[16 + m], w2 = Wp1[32 + m];
            float u0 = Wp2[3 * m], u1 = Wp2[3 * m + 1], u2 = Wp2[3 * m + 2];
            #pragma unroll
            for (int p = 0; p < 4; ++p) {
                float t = fmaf(r0[p], w0, fmaf(r1[p], w1, r2[p] * w2));
                t = gelu_poly(t);
                a0[p] = fmaf(t, u0, a0[p]);
                a1[p] = fmaf(t, u1, a1[p]);
                a2[p] = fmaf(t, u2, a2[p]);
            }
        }
        #pragma unroll
        for (int p = 0; p < 4; ++p) {
            pp0[p] = leaky_f(a0[p]); pp1[p] = leaky_f(a1[p]); pp2[p] = leaky_f(a2[p]);
        }
    }
    {   // neg branch
        float r0[4], r1[4], r2[4];
        float a0[4] = {}, a1[4] = {}, a2[4] = {};
        #pragma unroll
        for (int p = 0; p < 4; ++p) {
            r0[p] = fmaxf(-d0[p], 0.f); r1[p] = fmaxf(-d1[p], 0.f); r2[p] = fmaxf(-d2[p], 0.f);
        }
        #pragma unroll
        for (int m = 0; m < 16; ++m) {
            float w0 = Wn1[m], w1 = Wn1[16 + m], w2 = Wn1[32 + m];
            float u0 = Wn2[3 * m], u1 = Wn2[3 * m + 1], u2 = Wn2[3 * m + 2];
            #pragma unroll
            for (int p = 0; p < 4; ++p) {
                float t = fmaf(r0[p], w0, fmaf(r1[p], w1, r2[p] * w2));
                t = gelu_poly(t);
                a0[p] = fmaf(t, u0, a0[p]);
                a1[p] = fmaf(t, u1, a1[p]);
                a2[p] = fmaf(t, u2, a2[p]);
            }
        }
        #pragma unroll
        for (int p = 0; p < 4; ++p) {
            nv0[p] = leaky_f(a0[p]); nv1[p] = leaky_f(a1[p]); nv2[p] = leaky_f(a2[p]);
        }
    }
    float c00 = Wc[0], c01 = Wc[1], c02 = Wc[2];
    float c10 = Wc[3], c11 = Wc[4], c12 = Wc[5];
    float c20 = Wc[6], c21 = Wc[7], c22 = Wc[8];
    float b0 = bc[0], b1 = bc[1], b2 = bc[2];

    long base = (long)bi * NN;
    #pragma unroll
    for (int p = 0; p < 4; ++p) {
        int j = tid + p * 256;
        float q0 = pp0[p] * nv0[p], q1 = pp1[p] * nv1[p], q2 = pp2[p] * nv2[p];
        float c0 = leaky_f(fmaf(q0, c00, fmaf(q1, c10, fmaf(q2, c20, b0))));
        float c1 = leaky_f(fmaf(q0, c01, fmaf(q1, c11, fmaf(q2, c21, b1))));
        float c2 = leaky_f(fmaf(q0, c02, fmaf(q1, c12, fmaf(q2, c22, b2))));
        md[base + j]               = c0 * d0[p];
        md[MDPLANE + base + j]     = c1 * d1[p];
        md[2 * MDPLANE + base + j] = c2 * d2[p];
    }
}

// ---------------- K4: fused MFMA attention ----------------
__global__ __launch_bounds__(256) void attn_kernel(
    const __hip_bfloat16* __restrict__ q,
    const __hip_bfloat16* __restrict__ kk,
    const __hip_bfloat16* __restrict__ vt,
    const float* __restrict__ md,
    const float* __restrict__ Wsp,
    float* __restrict__ y)
{
    int it = blockIdx.x, h = blockIdx.y, b = blockIdx.z;
    int tid = threadIdx.x;
    int w = tid >> 6, lane = tid & 63;
    int g = lane >> 4, c = lane & 15;

    __shared__ __align__(16) __hip_bfloat16 k_lds[2][64][64];
    __shared__ __align__(16) __hip_bfloat16 v_lds[2][64][64];   // V^T tile: [d][j]
    __shared__ __align__(16) __hip_bfloat16 p_lds[4][16][64];

    const __hip_bfloat16* qp = q + ((long)(b * HEADS + h) * NN + it * 64) * DH;
    const __hip_bfloat16* kp = kk + (long)(b * HEADS + h) * NN * DH;
    const __hip_bfloat16* vp = vt + (long)(b * HEADS + h) * DH * NN;

    bf16x8 qa[2];
    #pragma unroll
    for (int t2 = 0; t2 < 2; ++t2)
        qa[t2] = *reinterpret_cast<const bf16x8*>(qp + (w * 16 + c) * DH + t2 * 32 + g * 8);

    int r0 = tid >> 3;
    int d00 = (tid & 7) * 8;
    int4 kreg[2], vreg[2];

    f32x4 o[4];
    #pragma unroll
    for (int df = 0; df < 4; ++df) { o[df][0] = 0.f; o[df][1] = 0.f; o[df][2] = 0.f; o[df][3] = 0.f; }
    float m_[4] = {-1e30f, -1e30f, -1e30f, -1e30f};
    float l_[4] = {0.f, 0.f, 0.f, 0.f};
    float wdx[4] = {0.f, 0.f, 0.f, 0.f}, wdy[4] = {0.f, 0.f, 0.f, 0.f}, wdz[4] = {0.f, 0.f, 0.f, 0.f};

    #pragma unroll
    for (int c2 = 0; c2 < 2; ++c2) {
        int r = r0 + c2 * 32;
        kreg[c2] = *reinterpret_cast<const int4*>(kp + (0 * 64 + r) * DH + d00);
        vreg[c2] = *reinterpret_cast<const int4*>(vp + (long)r * NN + 0 * 64 + d00);
    }
    #pragma unroll
    for (int c2 = 0; c2 < 2; ++c2) {
        int r = r0 + c2 * 32;
        int sd = d00 ^ ((r & 7) << 3);
        *reinterpret_cast<int4*>(&k_lds[0][r][sd]) = kreg[c2];
        *reinterpret_cast<int4*>(&v_lds[0][r][sd]) = vreg[c2];
    }
    __syncthreads();

    const float* md0 = md;
    const float* md1 = md + MDPLANE;
    const float* md2 = md + 2 * MDPLANE;
    long mdrow = (long)(b * NN + it * 64 + w * 16 + g * 4) * NN + c;

    for (int t = 0; t < NT; ++t) {
        int buf = t & 1;
        if (t + 1 < NT) {
            #pragma unroll
            for (int c2 = 0; c2 < 2; ++c2) {
                int r = r0 + c2 * 32;
                kreg[c2] = *reinterpret_cast<const int4*>(kp + ((t + 1) * 64 + r) * DH + d00);
                vreg[c2] = *reinterpret_cast<const int4*>(vp + (long)r * NN + (t + 1) * 64 + d00);
            }
        }

        f32x4 s[4];
        #pragma unroll
        for (int jf = 0; jf < 4; ++jf) {
            f32x4 acc = {0.f, 0.f, 0.f, 0.f};
            int jl = jf * 16 + c;
            int sw = (jl & 7) << 3;
            #pragma unroll
            for (int t2 = 0; t2 < 2; ++t2) {
                bf16x8 bk = *reinterpret_cast<const bf16x8*>(&k_lds[buf][jl][(t2 * 32 + g * 8) ^ sw]);
                acc = __builtin_amdgcn_mfma_f32_16x16x32_bf16(qa[t2], bk, acc, 0, 0, 0);
            }
            s[jf] = acc;
        }

        float pe[4][4];
        #pragma unroll
        for (int r = 0; r < 4; ++r) {
            float tm = fmaxf(fmaxf(s[0][r], s[1][r]), fmaxf(s[2][r], s[3][r]));
            tm = fmaxf(tm, __shfl_xor(tm, 1));
            tm = fmaxf(tm, __shfl_xor(tm, 2));
            tm = fmaxf(tm, __shfl_xor(tm, 4));
            tm = fmaxf(tm, __shfl_xor(tm, 8));
            float nm = fmaxf(m_[r], tm);
            float corr = __expf(m_[r] - nm);
            m_[r] = nm;
            l_[r] *= corr;
            wdx[r] *= corr; wdy[r] *= corr; wdz[r] *= corr;
            o[0][r] *= corr; o[1][r] *= corr; o[2][r] *= corr; o[3][r] *= corr;
            float ps = 0.f;
            #pragma unroll
            for (int jf = 0; jf < 4; ++jf) {
                float p = __expf(s[jf][r] - nm);
                pe[r][jf] = p;
                ps += p;
            }
            l_[r] += ps;
        }

        #pragma unroll
        for (int r = 0; r < 4; ++r) {
            int row = g * 4 + r;
            int sw = (row & 7) << 3;
            #pragma unroll
            for (int jf = 0; jf < 4; ++jf)
                p_lds[w][row][(jf * 16 + c) ^ sw] = __float2bfloat16(pe[r][jf]);
        }
        asm volatile("s_waitcnt lgkmcnt(0)" ::: "memory");

        #pragma unroll
        for (int r = 0; r < 4; ++r) {
            long off = mdrow + (long)r * NN + t * 64;
            #pragma unroll
            for (int jf = 0; jf < 4; ++jf) {
                float m0 = md0[off + jf * 16];
                float m1 = md1[off + jf * 16];
                float m2 = md2[off + jf * 16];
                wdx[r] = fmaf(pe[r][jf], m0, wdx[r]);
                wdy[r] = fmaf(pe[r][jf], m1, wdy[r]);
                wdz[r] = fmaf(pe[r][jf], m2, wdz[r]);
            }
        }

        #pragma unroll
        for (int t2 = 0; t2 < 2; ++t2) {
            int swp = (c & 7) << 3;
            bf16x8 pa = *reinterpret_cast<const bf16x8*>(&p_lds[w][c][(t2 * 32 + g * 8) ^ swp]);
            #pragma unroll
            for (int df = 0; df < 4; ++df) {
                int dl = df * 16 + c;
                int swv = (dl & 7) << 3;
                bf16x8 bv = *reinterpret_cast<const bf16x8*>(&v_lds[buf][dl][(t2 * 32 + g * 8) ^ swv]);
                o[df] = __builtin_amdgcn_mfma_f32_16x16x32_bf16(pa, bv, o[df], 0, 0, 0);
            }
        }

        if (t + 1 < NT) {
            #pragma unroll
            for (int c2 = 0; c2 < 2; ++c2) {
                int r = r0 + c2 * 32;
                int sd = d00 ^ ((r & 7) << 3);
                *reinterpret_cast<int4*>(&k_lds[buf ^ 1][r][sd]) = kreg[c2];
                *reinterpret_cast<int4*>(&v_lds[buf ^ 1][r][sd]) = vreg[c2];
            }
        }
        __syncthreads();
    }

    #pragma unroll
    for (int r = 0; r < 4; ++r) {
        float lv = l_[r];
        lv += __shfl_xor(lv, 1); lv += __shfl_xor(lv, 2);
        lv += __shfl_xor(lv, 4); lv += __shfl_xor(lv, 8);
        float w0 = wdx[r], w1 = wdy[r], w2 = wdz[r];
        w0 += __shfl_xor(w0, 1); w0 += __shfl_xor(w0, 2); w0 += __shfl_xor(w0, 4); w0 += __shfl_xor(w0, 8);
        w1 += __shfl_xor(w1, 1); w1 += __shfl_xor(w1, 2); w1 += __shfl_xor(w1, 4); w1 += __shfl_xor(w1, 8);
        w2 += __shfl_xor(w2, 1); w2 += __shfl_xor(w2, 2); w2 += __shfl_xor(w2, 4); w2 += __shfl_xor(w2, 8);
        float inv = 1.0f / lv;
        w0 *= inv; w1 *= inv; w2 *= inv;
        int row = g * 4 + r;
        long ig = (long)b * NN + it * 64 + w * 16 + row;
        float* yp = y + ig * INNERD + h * DH;
        #pragma unroll
        for (int df = 0; df < 4; ++df) {
            int d = df * 16 + c;
            float disp = w0 * Wsp[d] + w1 * Wsp[64 + d] + w2 * Wsp[128 + d];
            yp[d] = o[df][r] * inv + disp;
        }
    }
}

// ---------------- K5: output projection + GELU + residual ----------------
__global__ __launch_bounds__(256) void out_kernel(const float* __restrict__ y,
                                                  const float* __restrict__ Wout,
                                                  const float* __restrict__ bout,
                                                  const float* __restrict__ feat,
                                                  float* __restrict__ out) {
    __shared__ float ys[8][INNERD];
    int rt = blockIdx.x;
    int tid = threadIdx.x;
    for (int idx = tid; idx < 8 * INNERD; idx += 256) {
        int r = idx >> 9, c = idx & 511;
        ys[r][c] = y[((long)rt * 8 + r) * INNERD + c];
    }
    __syncthreads();
    float acc[8] = {};
    for (int kk = 0; kk < INNERD; kk += 4) {
        float w0 = Wout[(kk + 0) * DIMM + tid];
        float w1 = Wout[(kk + 1) * DIMM + tid];
        float w2 = Wout[(kk + 2) * DIMM + tid];
        float w3 = Wout[(kk + 3) * DIMM + tid];
        #pragma unroll
        for (int r = 0; r < 8; ++r) {
            float4 yv = *(const float4*)&ys[r][kk];
            acc[r] += yv.x * w0 + yv.y * w1 + yv.z * w2 + yv.w * w3;
        }
    }
    float bo = bout[tid];
    #pragma unroll
    for (int r = 0; r < 8; ++r) {
        long gidx = (long)rt * 8 + r;
        float val = gelu_poly(acc[r] + bo);
        out[gidx * DIMM + tid] = val + feat[gidx * DIMM + tid];
    }
}

extern "C" void kernel_launch(void* const* d_in, const int* in_sizes, int n_in,
                              void* d_out, int out_size, void* d_ws, size_t ws_size,
                              hipStream_t stream) {
    const float* xyzs  = (const float*)d_in[0];
    const float* feat  = (const float*)d_in[1];
    const float* gamma = (const float*)d_in[2];
    const float* beta  = (const float*)d_in[3];
    const float* Wqkv  = (const float*)d_in[4];
    const float* Wp1   = (const float*)d_in[5];
    const float* Wp2   = (const float*)d_in[6];
    const float* Wn1   = (const float*)d_in[7];
    const float* Wn2   = (const float*)d_in[8];
    const float* Wc    = (const float*)d_in[9];
    const float* bc    = (const float*)d_in[10];
    const float* Wsp   = (const float*)d_in[11];
    const float* Wout  = (const float*)d_in[12];
    const float* bout  = (const float*)d_in[13];
    float* out = (float*)d_out;

    // workspace: x (1M f32) | qb,kb,vtb (2M bf16 each) | y (2M f32) | md planar (3 x 4M f32)
    float* x = (float*)d_ws;
    __hip_bfloat16* qb  = (__hip_bfloat16*)(x + 1048576);
    __hip_bfloat16* kb  = qb + 2097152;
    __hip_bfloat16* vtb = kb + 2097152;
    float* y  = (float*)(vtb + 2097152);
    float* md = y + 2097152;

    ln_kernel<<<4096, 256, 0, stream>>>(feat, gamma, beta, x);
    qkv_kernel<<<dim3(256, 6), 256, 0, stream>>>(x, Wqkv, qb, kb, vtb);
    dmlp_kernel<<<4096, 256, 0, stream>>>(xyzs, Wp1, Wp2, Wn1, Wn2, Wc, bc, md);
    attn_kernel<<<dim3(16, HEADS, BB), 256, 0, stream>>>(qb, kb, vtb, md, Wsp, y);
    out_kernel<<<512, 256, 0, stream>>>(y, Wout, bout, feat, out);
}

// Round 5
// 177.607 us; speedup vs baseline: 9.1089x; 1.3393x over previous
//
#include <hip/hip_runtime.h>
#include <hip/hip_bf16.h>
#include <math.h>

#define BB 4
#define NN 1024
#define DIMM 256
#define HEADS 8
#define DH 64
#define INNERD 512
#define NT 16
#define MDPLANE 4194304   // B*N*N

typedef __bf16 bf16x8 __attribute__((ext_vector_type(8)));
typedef float f32x4 __attribute__((ext_vector_type(4)));

// Trans-free GELU: clamp to [-3,3] + degree-9 odd poly for erf(x/sqrt2).
__device__ __forceinline__ float gelu_poly(float x) {
    float xc = fminf(fmaxf(x, -3.0f), 3.0f);
    float u = xc * xc;
    float f = fmaf(u, fmaf(u, fmaf(u, fmaf(u, 4.4413e-5f, -1.33195e-3f),
                                   1.70980e-2f), -1.299964e-1f), 7.9734583e-1f);
    float E = xc * f;
    float hx = 0.5f * xc;
    float g = fmaf(hx, E, hx);
    return g + fmaxf(x - 3.0f, 0.0f);
}
__device__ __forceinline__ float leaky_f(float x) {
    return fmaxf(x, 0.01f * x);
}

// ---------------- K1: LayerNorm (bf16 out) ----------------
__global__ __launch_bounds__(256) void ln_kernel(const float* __restrict__ feat,
                                                 const float* __restrict__ gamma,
                                                 const float* __restrict__ beta,
                                                 __hip_bfloat16* __restrict__ xb) {
    int row = blockIdx.x;
    int t = threadIdx.x;
    float v = feat[row * DIMM + t];
    float s = v, ss = v * v;
    #pragma unroll
    for (int off = 1; off < 64; off <<= 1) {
        s += __shfl_xor(s, off);
        ss += __shfl_xor(ss, off);
    }
    __shared__ float red[2][4];
    int w = t >> 6, lane = t & 63;
    if (lane == 0) { red[0][w] = s; red[1][w] = ss; }
    __syncthreads();
    s = red[0][0] + red[0][1] + red[0][2] + red[0][3];
    ss = red[1][0] + red[1][1] + red[1][2] + red[1][3];
    float mu = s * (1.0f / DIMM);
    float var = ss * (1.0f / DIMM) - mu * mu;
    float rs = rsqrtf(var + 1e-5f);
    xb[row * DIMM + t] = __float2bfloat16((v - mu) * rs * gamma[t] + beta[t]);
}

// ---------------- K2a: transpose-convert Wqkv (256x1536 f32) -> Wt (1536x256 bf16) ----------------
__global__ __launch_bounds__(256) void wt_kernel(const float* __restrict__ W,
                                                 __hip_bfloat16* __restrict__ Wt) {
    __shared__ float tile[64][65];
    int n0 = blockIdx.x * 64, k0 = blockIdx.y * 64;
    int tid = threadIdx.x;
    int cc = tid & 63, rr = tid >> 6;
    #pragma unroll
    for (int p = 0; p < 16; ++p) {
        int k = rr + p * 4;
        tile[k][cc] = W[(k0 + k) * 1536 + n0 + cc];
    }
    __syncthreads();
    #pragma unroll
    for (int p = 0; p < 16; ++p) {
        int n = rr + p * 4;
        Wt[(n0 + n) * 256 + k0 + cc] = __float2bfloat16(tile[cc][n]);
    }
}

// ---------------- K2b: MFMA qkv GEMM: C(4096x1536) = xb(4096x256) @ Wt^T ----------------
// grid (64 m-tiles, 24 n-tiles), block 256 = 4 waves; wave = 16 rows x 64 cols; no LDS.
__global__ __launch_bounds__(256) void qkv_gemm(const __hip_bfloat16* __restrict__ xb,
                                                const __hip_bfloat16* __restrict__ Wt,
                                                __hip_bfloat16* __restrict__ qb,
                                                __hip_bfloat16* __restrict__ kb,
                                                __hip_bfloat16* __restrict__ vb) {
    int mt = blockIdx.x, nt = blockIdx.y;
    int tid = threadIdx.x, w = tid >> 6, lane = tid & 63;
    int g = lane >> 4, c = lane & 15;

    const __hip_bfloat16* ap = xb + (mt * 64 + w * 16 + c) * 256 + g * 8;
    bf16x8 a[8];
    #pragma unroll
    for (int ks = 0; ks < 8; ++ks) a[ks] = *reinterpret_cast<const bf16x8*>(ap + ks * 32);

    f32x4 acc[4];
    #pragma unroll
    for (int jf = 0; jf < 4; ++jf) { acc[jf][0] = 0.f; acc[jf][1] = 0.f; acc[jf][2] = 0.f; acc[jf][3] = 0.f; }

    const __hip_bfloat16* bp = Wt + (nt * 64 + c) * 256 + g * 8;
    #pragma unroll
    for (int jf = 0; jf < 4; ++jf) {
        const __hip_bfloat16* bpj = bp + jf * 16 * 256;
        #pragma unroll
        for (int ks = 0; ks < 8; ++ks) {
            bf16x8 bfrag = *reinterpret_cast<const bf16x8*>(bpj + ks * 32);
            acc[jf] = __builtin_amdgcn_mfma_f32_16x16x32_bf16(a[ks], bfrag, acc[jf], 0, 0, 0);
        }
    }

    int col0 = nt * 64;
    int part = col0 >> 9;            // 0=q,1=k,2=v
    int h = (col0 >> 6) & 7;
    __hip_bfloat16* dst = part == 0 ? qb : (part == 1 ? kb : vb);
    float sc = part == 0 ? 0.125f : 1.0f;
    #pragma unroll
    for (int jf = 0; jf < 4; ++jf) {
        int d = jf * 16 + c;
        #pragma unroll
        for (int r = 0; r < 4; ++r) {
            int m = mt * 64 + w * 16 + g * 4 + r;
            int b = m >> 10, nn = m & 1023;
            dst[(((b * HEADS + h) * NN) + nn) * DH + d] = __float2bfloat16(acc[jf][r] * sc);
        }
    }
}

// ---------------- K2c: transpose vb[b,h,n,d] -> vtb[b,h,d,n] (bf16) ----------------
__global__ __launch_bounds__(256) void vt_kernel(const __hip_bfloat16* __restrict__ vb,
                                                 __hip_bfloat16* __restrict__ vtb) {
    __shared__ __hip_bfloat16 tile[64][66];
    int ntile = blockIdx.x, h = blockIdx.y, b = blockIdx.z;
    int tid = threadIdx.x;
    int cc = tid & 63, rr = tid >> 6;
    const __hip_bfloat16* src = vb + ((long)(b * HEADS + h) * NN + ntile * 64) * DH;
    #pragma unroll
    for (int p = 0; p < 16; ++p) {
        int n = rr + p * 4;
        tile[n][cc] = src[n * DH + cc];
    }
    __syncthreads();
    __hip_bfloat16* dst = vtb + (long)(b * HEADS + h) * DH * NN + ntile * 64;
    #pragma unroll
    for (int p = 0; p < 16; ++p) {
        int d = rr + p * 4;
        dst[(long)d * NN + cc] = tile[cc][d];
    }
}

// ---------------- K3: pairwise delta MLP -> planar md[3][b,i,j] ----------------
__global__ __launch_bounds__(256) void dmlp_kernel(const float* __restrict__ xyz,
                                                   const float* __restrict__ Wp1,
                                                   const float* __restrict__ Wp2,
                                                   const float* __restrict__ Wn1,
                                                   const float* __restrict__ Wn2,
                                                   const float* __restrict__ Wc,
                                                   const float* __restrict__ bc,
                                                   float* __restrict__ md) {
    int tid = threadIdx.x;
    int bi = blockIdx.x;            // b*N + i
    int b = bi >> 10;
    const float* xj = xyz + (long)b * NN * 3;
    float xi0 = xyz[bi * 3 + 0], xi1 = xyz[bi * 3 + 1], xi2 = xyz[bi * 3 + 2];

    float d0[4], d1[4], d2[4];
    #pragma unroll
    for (int p = 0; p < 4; ++p) {
        int j = tid + p * 256;
        d0[p] = xj[j * 3 + 0] - xi0;
        d1[p] = xj[j * 3 + 1] - xi1;
        d2[p] = xj[j * 3 + 2] - xi2;
    }

    float pp0[4], pp1[4], pp2[4], nv0[4], nv1[4], nv2[4];
    {   // pos branch
        float r0[4], r1[4], r2[4];
        float a0[4] = {}, a1[4] = {}, a2[4] = {};
        #pragma unroll
        for (int p = 0; p < 4; ++p) {
            r0[p] = fmaxf(d0[p], 0.f); r1[p] = fmaxf(d1[p], 0.f); r2[p] = fmaxf(d2[p], 0.f);
        }
        #pragma unroll
        for (int m = 0; m < 16; ++m) {
            float w0 = Wp1[m], w1 = Wp1[16 + m], w2 = Wp1[32 + m];
            float u0 = Wp2[3 * m], u1 = Wp2[3 * m + 1], u2 = Wp2[3 * m + 2];
            #pragma unroll
            for (int p = 0; p < 4; ++p) {
                float t = fmaf(r0[p], w0, fmaf(r1[p], w1, r2[p] * w2));
                t = gelu_poly(t);
                a0[p] = fmaf(t, u0, a0[p]);
                a1[p] = fmaf(t, u1, a1[p]);
                a2[p] = fmaf(t, u2, a2[p]);
            }
        }
        #pragma unroll
        for (int p = 0; p < 4; ++p) {
            pp0[p] = leaky_f(a0[p]); pp1[p] = leaky_f(a1[p]); pp2[p] = leaky_f(a2[p]);
        }
    }
    {   // neg branch
        float r0[4], r1[4], r2[4];
        float a0[4] = {}, a1[4] = {}, a2[4] = {};
        #pragma unroll
        for (int p = 0; p < 4; ++p) {
            r0[p] = fmaxf(-d0[p], 0.f); r1[p] = fmaxf(-d1[p], 0.f); r2[p] = fmaxf(-d2[p], 0.f);
        }
        #pragma unroll
        for (int m = 0; m < 16; ++m) {
            float w0 = Wn1[m], w1 = Wn1[16 + m], w2 = Wn1[32 + m];
            float u0 = Wn2[3 * m], u1 = Wn2[3 * m + 1], u2 = Wn2[3 * m + 2];
            #pragma unroll
            for (int p = 0; p < 4; ++p) {
                float t = fmaf(r0[p], w0, fmaf(r1[p], w1, r2[p] * w2));
                t = gelu_poly(t);
                a0[p] = fmaf(t, u0, a0[p]);
                a1[p] = fmaf(t, u1, a1[p]);
                a2[p] = fmaf(t, u2, a2[p]);
            }
        }
        #pragma unroll
        for (int p = 0; p < 4; ++p) {
            nv0[p] = leaky_f(a0[p]); nv1[p] = leaky_f(a1[p]); nv2[p] = leaky_f(a2[p]);
        }
    }
    float c00 = Wc[0], c01 = Wc[1], c02 = Wc[2];
    float c10 = Wc[3], c11 = Wc[4], c12 = Wc[5];
    float c20 = Wc[6], c21 = Wc[7], c22 = Wc[8];
    float b0 = bc[0], b1 = bc[1], b2 = bc[2];

    long base = (long)bi * NN;
    #pragma unroll
    for (int p = 0; p < 4; ++p) {
        int j = tid + p * 256;
        float q0 = pp0[p] * nv0[p], q1 = pp1[p] * nv1[p], q2 = pp2[p] * nv2[p];
        float c0 = leaky_f(fmaf(q0, c00, fmaf(q1, c10, fmaf(q2, c20, b0))));
        float c1 = leaky_f(fmaf(q0, c01, fmaf(q1, c11, fmaf(q2, c21, b1))));
        float c2 = leaky_f(fmaf(q0, c02, fmaf(q1, c12, fmaf(q2, c22, b2))));
        md[base + j]               = c0 * d0[p];
        md[MDPLANE + base + j]     = c1 * d1[p];
        md[2 * MDPLANE + base + j] = c2 * d2[p];
    }
}

// ---------------- K4: fused MFMA attention ----------------
__global__ __launch_bounds__(256) void attn_kernel(
    const __hip_bfloat16* __restrict__ q,
    const __hip_bfloat16* __restrict__ kk,
    const __hip_bfloat16* __restrict__ vt,
    const float* __restrict__ md,
    const float* __restrict__ Wsp,
    float* __restrict__ y)
{
    int it = blockIdx.x, h = blockIdx.y, b = blockIdx.z;
    int tid = threadIdx.x;
    int w = tid >> 6, lane = tid & 63;
    int g = lane >> 4, c = lane & 15;

    __shared__ __align__(16) __hip_bfloat16 k_lds[2][64][64];
    __shared__ __align__(16) __hip_bfloat16 v_lds[2][64][64];   // V^T tile: [d][j]
    __shared__ __align__(16) __hip_bfloat16 p_lds[4][16][64];

    const __hip_bfloat16* qp = q + ((long)(b * HEADS + h) * NN + it * 64) * DH;
    const __hip_bfloat16* kp = kk + (long)(b * HEADS + h) * NN * DH;
    const __hip_bfloat16* vp = vt + (long)(b * HEADS + h) * DH * NN;

    bf16x8 qa[2];
    #pragma unroll
    for (int t2 = 0; t2 < 2; ++t2)
        qa[t2] = *reinterpret_cast<const bf16x8*>(qp + (w * 16 + c) * DH + t2 * 32 + g * 8);

    int r0 = tid >> 3;
    int d00 = (tid & 7) * 8;
    int4 kreg[2], vreg[2];

    f32x4 o[4];
    #pragma unroll
    for (int df = 0; df < 4; ++df) { o[df][0] = 0.f; o[df][1] = 0.f; o[df][2] = 0.f; o[df][3] = 0.f; }
    float m_[4] = {-1e30f, -1e30f, -1e30f, -1e30f};
    float l_[4] = {0.f, 0.f, 0.f, 0.f};
    float wdx[4] = {0.f, 0.f, 0.f, 0.f}, wdy[4] = {0.f, 0.f, 0.f, 0.f}, wdz[4] = {0.f, 0.f, 0.f, 0.f};

    #pragma unroll
    for (int c2 = 0; c2 < 2; ++c2) {
        int r = r0 + c2 * 32;
        kreg[c2] = *reinterpret_cast<const int4*>(kp + (0 * 64 + r) * DH + d00);
        vreg[c2] = *reinterpret_cast<const int4*>(vp + (long)r * NN + 0 * 64 + d00);
    }
    #pragma unroll
    for (int c2 = 0; c2 < 2; ++c2) {
        int r = r0 + c2 * 32;
        int sd = d00 ^ ((r & 7) << 3);
        *reinterpret_cast<int4*>(&k_lds[0][r][sd]) = kreg[c2];
        *reinterpret_cast<int4*>(&v_lds[0][r][sd]) = vreg[c2];
    }
    __syncthreads();

    const float* md0 = md;
    const float* md1 = md + MDPLANE;
    const float* md2 = md + 2 * MDPLANE;
    long mdrow = (long)(b * NN + it * 64 + w * 16 + g * 4) * NN + c;

    for (int t = 0; t < NT; ++t) {
        int buf = t & 1;
        if (t + 1 < NT) {
            #pragma unroll
            for (int c2 = 0; c2 < 2; ++c2) {
                int r = r0 + c2 * 32;
                kreg[c2] = *reinterpret_cast<const int4*>(kp + ((t + 1) * 64 + r) * DH + d00);
                vreg[c2] = *reinterpret_cast<const int4*>(vp + (long)r * NN + (t + 1) * 64 + d00);
            }
        }

        f32x4 s[4];
        #pragma unroll
        for (int jf = 0; jf < 4; ++jf) {
            f32x4 acc = {0.f, 0.f, 0.f, 0.f};
            int jl = jf * 16 + c;
            int sw = (jl & 7) << 3;
            #pragma unroll
            for (int t2 = 0; t2 < 2; ++t2) {
                bf16x8 bk = *reinterpret_cast<const bf16x8*>(&k_lds[buf][jl][(t2 * 32 + g * 8) ^ sw]);
                acc = __builtin_amdgcn_mfma_f32_16x16x32_bf16(qa[t2], bk, acc, 0, 0, 0);
            }
            s[jf] = acc;
        }

        float pe[4][4];
        #pragma unroll
        for (int r = 0; r < 4; ++r) {
            float tm = fmaxf(fmaxf(s[0][r], s[1][r]), fmaxf(s[2][r], s[3][r]));
            tm = fmaxf(tm, __shfl_xor(tm, 1));
            tm = fmaxf(tm, __shfl_xor(tm, 2));
            tm = fmaxf(tm, __shfl_xor(tm, 4));
            tm = fmaxf(tm, __shfl_xor(tm, 8));
            float nm = fmaxf(m_[r], tm);
            float corr = __expf(m_[r] - nm);
            m_[r] = nm;
            l_[r] *= corr;
            wdx[r] *= corr; wdy[r] *= corr; wdz[r] *= corr;
            o[0][r] *= corr; o[1][r] *= corr; o[2][r] *= corr; o[3][r] *= corr;
            float ps = 0.f;
            #pragma unroll
            for (int jf = 0; jf < 4; ++jf) {
                float p = __expf(s[jf][r] - nm);
                pe[r][jf] = p;
                ps += p;
            }
            l_[r] += ps;
        }

        #pragma unroll
        for (int r = 0; r < 4; ++r) {
            int row = g * 4 + r;
            int sw = (row & 7) << 3;
            #pragma unroll
            for (int jf = 0; jf < 4; ++jf)
                p_lds[w][row][(jf * 16 + c) ^ sw] = __float2bfloat16(pe[r][jf]);
        }
        asm volatile("s_waitcnt lgkmcnt(0)" ::: "memory");

        #pragma unroll
        for (int r = 0; r < 4; ++r) {
            long off = mdrow + (long)r * NN + t * 64;
            #pragma unroll
            for (int jf = 0; jf < 4; ++jf) {
                float m0 = md0[off + jf * 16];
                float m1 = md1[off + jf * 16];
                float m2 = md2[off + jf * 16];
                wdx[r] = fmaf(pe[r][jf], m0, wdx[r]);
                wdy[r] = fmaf(pe[r][jf], m1, wdy[r]);
                wdz[r] = fmaf(pe[r][jf], m2, wdz[r]);
            }
        }

        #pragma unroll
        for (int t2 = 0; t2 < 2; ++t2) {
            int swp = (c & 7) << 3;
            bf16x8 pa = *reinterpret_cast<const bf16x8*>(&p_lds[w][c][(t2 * 32 + g * 8) ^ swp]);
            #pragma unroll
            for (int df = 0; df < 4; ++df) {
                int dl = df * 16 + c;
                int swv = (dl & 7) << 3;
                bf16x8 bv = *reinterpret_cast<const bf16x8*>(&v_lds[buf][dl][(t2 * 32 + g * 8) ^ swv]);
                o[df] = __builtin_amdgcn_mfma_f32_16x16x32_bf16(pa, bv, o[df], 0, 0, 0);
            }
        }

        if (t + 1 < NT) {
            #pragma unroll
            for (int c2 = 0; c2 < 2; ++c2) {
                int r = r0 + c2 * 32;
                int sd = d00 ^ ((r & 7) << 3);
                *reinterpret_cast<int4*>(&k_lds[buf ^ 1][r][sd]) = kreg[c2];
                *reinterpret_cast<int4*>(&v_lds[buf ^ 1][r][sd]) = vreg[c2];
            }
        }
        __syncthreads();
    }

    #pragma unroll
    for (int r = 0; r < 4; ++r) {
        float lv = l_[r];
        lv += __shfl_xor(lv, 1); lv += __shfl_xor(lv, 2);
        lv += __shfl_xor(lv, 4); lv += __shfl_xor(lv, 8);
        float w0 = wdx[r], w1 = wdy[r], w2 = wdz[r];
        w0 += __shfl_xor(w0, 1); w0 += __shfl_xor(w0, 2); w0 += __shfl_xor(w0, 4); w0 += __shfl_xor(w0, 8);
        w1 += __shfl_xor(w1, 1); w1 += __shfl_xor(w1, 2); w1 += __shfl_xor(w1, 4); w1 += __shfl_xor(w1, 8);
        w2 += __shfl_xor(w2, 1); w2 += __shfl_xor(w2, 2); w2 += __shfl_xor(w2, 4); w2 += __shfl_xor(w2, 8);
        float inv = 1.0f / lv;
        w0 *= inv; w1 *= inv; w2 *= inv;
        int row = g * 4 + r;
        long ig = (long)b * NN + it * 64 + w * 16 + row;
        float* yp = y + ig * INNERD + h * DH;
        #pragma unroll
        for (int df = 0; df < 4; ++df) {
            int d = df * 16 + c;
            float disp = w0 * Wsp[d] + w1 * Wsp[64 + d] + w2 * Wsp[128 + d];
            yp[d] = o[df][r] * inv + disp;
        }
    }
}

// ---------------- K5: output projection + GELU + residual ----------------
__global__ __launch_bounds__(256) void out_kernel(const float* __restrict__ y,
                                                  const float* __restrict__ Wout,
                                                  const float* __restrict__ bout,
                                                  const float* __restrict__ feat,
                                                  float* __restrict__ out) {
    __shared__ float ys[8][INNERD];
    int rt = blockIdx.x;
    int tid = threadIdx.x;
    for (int idx = tid; idx < 8 * INNERD; idx += 256) {
        int r = idx >> 9, c = idx & 511;
        ys[r][c] = y[((long)rt * 8 + r) * INNERD + c];
    }
    __syncthreads();
    float acc[8] = {};
    for (int kk = 0; kk < INNERD; kk += 4) {
        float w0 = Wout[(kk + 0) * DIMM + tid];
        float w1 = Wout[(kk + 1) * DIMM + tid];
        float w2 = Wout[(kk + 2) * DIMM + tid];
        float w3 = Wout[(kk + 3) * DIMM + tid];
        #pragma unroll
        for (int r = 0; r < 8; ++r) {
            float4 yv = *(const float4*)&ys[r][kk];
            acc[r] += yv.x * w0 + yv.y * w1 + yv.z * w2 + yv.w * w3;
        }
    }
    float bo = bout[tid];
    #pragma unroll
    for (int r = 0; r < 8; ++r) {
        long gidx = (long)rt * 8 + r;
        float val = gelu_poly(acc[r] + bo);
        out[gidx * DIMM + tid] = val + feat[gidx * DIMM + tid];
    }
}

extern "C" void kernel_launch(void* const* d_in, const int* in_sizes, int n_in,
                              void* d_out, int out_size, void* d_ws, size_t ws_size,
                              hipStream_t stream) {
    const float* xyzs  = (const float*)d_in[0];
    const float* feat  = (const float*)d_in[1];
    const float* gamma = (const float*)d_in[2];
    const float* beta  = (const float*)d_in[3];
    const float* Wqkv  = (const float*)d_in[4];
    const float* Wp1   = (const float*)d_in[5];
    const float* Wp2   = (const float*)d_in[6];
    const float* Wn1   = (const float*)d_in[7];
    const float* Wn2   = (const float*)d_in[8];
    const float* Wc    = (const float*)d_in[9];
    const float* bc    = (const float*)d_in[10];
    const float* Wsp   = (const float*)d_in[11];
    const float* Wout  = (const float*)d_in[12];
    const float* bout  = (const float*)d_in[13];
    float* out = (float*)d_out;

    // workspace (bf16 elems unless noted): xb 1M | Wt 384K | qb,kb,vb,vtb 2M each | y 2M f32 | md 12M f32
    __hip_bfloat16* xb  = (__hip_bfloat16*)d_ws;
    __hip_bfloat16* Wt  = xb + 1048576;
    __hip_bfloat16* qb  = Wt + 393216;
    __hip_bfloat16* kb  = qb + 2097152;
    __hip_bfloat16* vb  = kb + 2097152;
    __hip_bfloat16* vtb = vb + 2097152;
    float* y  = (float*)(vtb + 2097152);
    float* md = y + 2097152;

    ln_kernel<<<4096, 256, 0, stream>>>(feat, gamma, beta, xb);
    wt_kernel<<<dim3(24, 4), 256, 0, stream>>>(Wqkv, Wt);
    qkv_gemm<<<dim3(64, 24), 256, 0, stream>>>(xb, Wt, qb, kb, vb);
    vt_kernel<<<dim3(16, HEADS, BB), 256, 0, stream>>>(vb, vtb);
    dmlp_kernel<<<4096, 256, 0, stream>>>(xyzs, Wp1, Wp2, Wn1, Wn2, Wc, bc, md);
    attn_kernel<<<dim3(16, HEADS, BB), 256, 0, stream>>>(qb, kb, vtb, md, Wsp, y);
    out_kernel<<<512, 256, 0, stream>>>(y, Wout, bout, feat, out);
}